// Round 3
// baseline (810.159 us; speedup 1.0000x reference)
//
#include <hip/hip_runtime.h>

// Problem constants: B=8, C=768, NH=12, WS=8, NC=1, H=W=64
#define B_    8
#define C_    768
#define NH_   12
#define HW_   4096
#define NTOK  4097
#define MTOT  32776         // B_ * NTOK
#define NEGV  (-10000.0f)
#define NSPLIT 16

typedef __bf16 bf16x8 __attribute__((ext_vector_type(8)));
typedef float  f32x4  __attribute__((ext_vector_type(4)));
typedef unsigned short us8 __attribute__((ext_vector_type(8)));

// addrspace casts for global_load_lds
#define GLB(p) ((const __attribute__((address_space(1))) void*)(p))
#define LDS(p) ((__attribute__((address_space(3))) void*)(p))

__device__ __forceinline__ float us2f(unsigned short u) {
    unsigned int v = ((unsigned int)u) << 16;
    float f; __builtin_memcpy(&f, &v, 4);
    return f;
}
__device__ __forceinline__ unsigned short f2us(float f) {
    unsigned int v; __builtin_memcpy(&v, &f, 4);
    v += 0x7FFFu + ((v >> 16) & 1u);   // RNE
    return (unsigned short)(v >> 16);
}

// ---------------------------------------------------------------------------
// Runtime dtype detect (flag=1 -> fp32 inputs).
// ---------------------------------------------------------------------------
__global__ __launch_bounds__(256) void detect_dtype(
    const unsigned int* __restrict__ xw, int* __restrict__ flag)
{
    __shared__ int s[256];
    int t = threadIdx.x, cnt = 0;
    for (int i = t; i < 4096; i += 256) {
        unsigned e = (xw[i] >> 23) & 0xFFu;
        cnt += (e >= 64u && e <= 191u) ? 1 : 0;
    }
    s[t] = cnt; __syncthreads();
    for (int k = 128; k > 0; k >>= 1) { if (t < k) s[t] += s[t + k]; __syncthreads(); }
    if (t == 0) *flag = (s[0] > 2048) ? 1 : 0;
}

// ---------------------------------------------------------------------------
// Generic weight transpose: src (Kd x Nd, flag dtype) -> dst (Nd x Kd, bf16)
// ---------------------------------------------------------------------------
__global__ __launch_bounds__(256) void transpose_w(
    const unsigned short* __restrict__ s16, const float* __restrict__ s32,
    const int* __restrict__ flagp, unsigned short* __restrict__ dst,
    int Kd, int Nd)
{
    int o = blockIdx.x * 256 + threadIdx.x;
    if (o >= Kd * Nd) return;
    int n = o / Kd, k = o % Kd;
    dst[o] = (*flagp) ? f2us(s32[(size_t)k * Nd + n]) : s16[(size_t)k * Nd + n];
}

// ---------------------------------------------------------------------------
// Fast GEMM: 128x128x32 tiles, 4 waves, 16x16x32 MFMA. 2-phase double-buffered
// pipeline (T3 minimum recipe): issue tile k+1's global_load_lds BEFORE tile
// k's ds_read+MFMA so load latency hides under compute; __syncthreads() at
// iteration end drains what's left. LDS 2x(8+8)=32 KB -> 5 blocks/CU.
// ---------------------------------------------------------------------------
__global__ __launch_bounds__(256) void gemm_bt(
    const unsigned short* __restrict__ A16, const float* __restrict__ A32,
    const int* __restrict__ aflagp,
    const unsigned short* __restrict__ BT,
    const unsigned short* __restrict__ bias16, const float* __restrict__ bias32,
    const int* __restrict__ bflagp,
    void* __restrict__ Cout, const int* __restrict__ oflagp,
    int M, int Nd, int K, long arow0)
{
    __shared__ __align__(16) unsigned short As[2][128 * 32];   // 2 x 8 KB
    __shared__ __align__(16) unsigned short Bs[2][128 * 32];   // 2 x 8 KB

    const int fa = aflagp ? *aflagp : 0;
    const int fb = bflagp ? *bflagp : 0;
    const int fo = oflagp ? *oflagp : 0;

    const int t    = threadIdx.x;
    const int m0   = blockIdx.y * 128;
    const int n0   = blockIdx.x * 128;
    const int wave = t >> 6;
    const int lane = t & 63;
    const int wm   = (wave >> 1) * 64;
    const int wn   = (wave & 1) * 64;
    const int frow = lane & 15;
    const int koff = (lane >> 4) * 8;

    f32x4 acc[4][4];
#pragma unroll
    for (int i = 0; i < 4; ++i)
#pragma unroll
        for (int j = 0; j < 4; ++j) acc[i][j] = (f32x4)0.0f;

    const int sr = t >> 2;
    const int sc = (t & 3) * 8;
    const int t8 = t * 8;

    int ga0 = m0 + sr;       if (ga0 >= M)  ga0 = M - 1;
    int ga1 = m0 + sr + 64;  if (ga1 >= M)  ga1 = M - 1;
    int gb0 = n0 + sr;       if (gb0 >= Nd) gb0 = Nd - 1;
    int gb1 = n0 + sr + 64;  if (gb1 >= Nd) gb1 = Nd - 1;

    const unsigned short* a0p = A16 + (size_t)(arow0 + ga0) * K + sc;
    const unsigned short* a1p = A16 + (size_t)(arow0 + ga1) * K + sc;
    const float*          a0f = A32 + (size_t)(arow0 + ga0) * K + sc;
    const float*          a1f = A32 + (size_t)(arow0 + ga1) * K + sc;
    const unsigned short* b0p = BT + (size_t)gb0 * K + sc;
    const unsigned short* b1p = BT + (size_t)gb1 * K + sc;

    if (!fa) {
        // ---- 2-phase pipelined path (bf16 A) ----
        const int NT = K >> 5;
        // prologue: stage tile 0 into buffer 0
        __builtin_amdgcn_global_load_lds(GLB(a0p), LDS(&As[0][t8]),        16, 0, 0);
        __builtin_amdgcn_global_load_lds(GLB(a1p), LDS(&As[0][t8 + 2048]), 16, 0, 0);
        __builtin_amdgcn_global_load_lds(GLB(b0p), LDS(&Bs[0][t8]),        16, 0, 0);
        __builtin_amdgcn_global_load_lds(GLB(b1p), LDS(&Bs[0][t8 + 2048]), 16, 0, 0);
        __syncthreads();

        int cur = 0;
        for (int kt = 0; kt < NT - 1; ++kt) {
            const int nk  = (kt + 1) << 5;
            const int nxt = cur ^ 1;
            // issue next tile's loads FIRST (latency overlaps compute below)
            __builtin_amdgcn_global_load_lds(GLB(a0p + nk), LDS(&As[nxt][t8]),        16, 0, 0);
            __builtin_amdgcn_global_load_lds(GLB(a1p + nk), LDS(&As[nxt][t8 + 2048]), 16, 0, 0);
            __builtin_amdgcn_global_load_lds(GLB(b0p + nk), LDS(&Bs[nxt][t8]),        16, 0, 0);
            __builtin_amdgcn_global_load_lds(GLB(b1p + nk), LDS(&Bs[nxt][t8 + 2048]), 16, 0, 0);

            bf16x8 af[4], bfr[4];
#pragma unroll
            for (int i = 0; i < 4; ++i)
                af[i] = *reinterpret_cast<const bf16x8*>(&As[cur][(wm + i * 16 + frow) * 32 + koff]);
#pragma unroll
            for (int j = 0; j < 4; ++j)
                bfr[j] = *reinterpret_cast<const bf16x8*>(&Bs[cur][(wn + j * 16 + frow) * 32 + koff]);
#pragma unroll
            for (int i = 0; i < 4; ++i)
#pragma unroll
                for (int j = 0; j < 4; ++j)
                    acc[i][j] = __builtin_amdgcn_mfma_f32_16x16x32_bf16(af[i], bfr[j], acc[i][j], 0, 0, 0);

            __syncthreads();   // drains staged loads (mostly landed) + syncs reuse
            cur = nxt;
        }
        // epilogue tile: compute only
        {
            bf16x8 af[4], bfr[4];
#pragma unroll
            for (int i = 0; i < 4; ++i)
                af[i] = *reinterpret_cast<const bf16x8*>(&As[cur][(wm + i * 16 + frow) * 32 + koff]);
#pragma unroll
            for (int j = 0; j < 4; ++j)
                bfr[j] = *reinterpret_cast<const bf16x8*>(&Bs[cur][(wn + j * 16 + frow) * 32 + koff]);
#pragma unroll
            for (int i = 0; i < 4; ++i)
#pragma unroll
                for (int j = 0; j < 4; ++j)
                    acc[i][j] = __builtin_amdgcn_mfma_f32_16x16x32_bf16(af[i], bfr[j], acc[i][j], 0, 0, 0);
        }
    } else {
        // ---- legacy single-buffer path (fp32 A fallback) ----
        for (int k0 = 0; k0 < K; k0 += 32) {
            unsigned short tmp[8];
#pragma unroll
            for (int e = 0; e < 8; ++e) tmp[e] = f2us(a0f[k0 + e]);
            *reinterpret_cast<us8*>(&As[0][sr * 32 + sc]) = *reinterpret_cast<us8*>(tmp);
#pragma unroll
            for (int e = 0; e < 8; ++e) tmp[e] = f2us(a1f[k0 + e]);
            *reinterpret_cast<us8*>(&As[0][(sr + 64) * 32 + sc]) = *reinterpret_cast<us8*>(tmp);
            __builtin_amdgcn_global_load_lds(GLB(b0p + k0), LDS(&Bs[0][t8]),        16, 0, 0);
            __builtin_amdgcn_global_load_lds(GLB(b1p + k0), LDS(&Bs[0][t8 + 2048]), 16, 0, 0);
            __syncthreads();

            bf16x8 af[4], bfr[4];
#pragma unroll
            for (int i = 0; i < 4; ++i)
                af[i] = *reinterpret_cast<const bf16x8*>(&As[0][(wm + i * 16 + frow) * 32 + koff]);
#pragma unroll
            for (int j = 0; j < 4; ++j)
                bfr[j] = *reinterpret_cast<const bf16x8*>(&Bs[0][(wn + j * 16 + frow) * 32 + koff]);
#pragma unroll
            for (int i = 0; i < 4; ++i)
#pragma unroll
                for (int j = 0; j < 4; ++j)
                    acc[i][j] = __builtin_amdgcn_mfma_f32_16x16x32_bf16(af[i], bfr[j], acc[i][j], 0, 0, 0);
            __syncthreads();
        }
    }

    const int crow = (lane >> 4) * 4;
    const int ccol = lane & 15;
    unsigned short* C16 = (unsigned short*)Cout;
    float*          C32 = (float*)Cout;
#pragma unroll
    for (int i = 0; i < 4; ++i)
#pragma unroll
        for (int j = 0; j < 4; ++j) {
            int gn = n0 + wn + j * 16 + ccol;
            float bv = 0.0f;
            if (bias16) bv = fb ? bias32[gn] : us2f(bias16[gn]);
#pragma unroll
            for (int r = 0; r < 4; ++r) {
                int gm = m0 + wm + i * 16 + crow + r;
                if (gm < M) {
                    float v = acc[i][j][r] + bv;
                    if (fo) C32[(size_t)gm * Nd + gn] = v;
                    else    C16[(size_t)gm * Nd + gn] = f2us(v);
                }
            }
        }
}

// ---------------------------------------------------------------------------
// Universal GEMM (fallback for proj when ws too small for pwT).
// ---------------------------------------------------------------------------
#define LSTR 40   // 32+8 pad; 80 B rows, 16B-aligned

__global__ __launch_bounds__(256) void gemm_univ(
    const unsigned short* __restrict__ A16, const float* __restrict__ A32,
    const int* __restrict__ aflagp,
    const unsigned short* __restrict__ B16, const float* __restrict__ B32,
    const int* __restrict__ bflagp, int btmode,
    const unsigned short* __restrict__ bias16, const float* __restrict__ bias32,
    void* __restrict__ Cout, const int* __restrict__ oflagp,
    int M, int Nd, int K, long arow0)
{
    __shared__ __align__(16) unsigned short As[128 * LSTR];
    __shared__ __align__(16) unsigned short Bs[128 * LSTR];

    const int fa = aflagp ? *aflagp : 0;
    const int fb = bflagp ? *bflagp : 0;
    const int fo = oflagp ? *oflagp : 0;

    const int t    = threadIdx.x;
    const int m0   = blockIdx.y * 128;
    const int n0   = blockIdx.x * 128;
    const int wave = t >> 6;
    const int lane = t & 63;
    const int wm   = (wave >> 1) * 64;
    const int wn   = (wave & 1) * 64;
    const int frow = lane & 15;
    const int koff = (lane >> 4) * 8;

    f32x4 acc[4][4];
#pragma unroll
    for (int i = 0; i < 4; ++i)
#pragma unroll
        for (int j = 0; j < 4; ++j) acc[i][j] = (f32x4)0.0f;

    const int sr = t >> 2;
    const int sc = (t & 3) * 8;

    for (int k0 = 0; k0 < K; k0 += 32) {
#pragma unroll
        for (int it = 0; it < 2; ++it) {
            int r = sr + it * 64;
            int gl = m0 + r; if (gl >= M) gl = M - 1;
            size_t grow = (size_t)(arow0 + gl);
            if (fa) {
                const float* p = &A32[grow * K + k0 + sc];
                unsigned short tmp[8];
#pragma unroll
                for (int e = 0; e < 8; ++e) tmp[e] = f2us(p[e]);
                *reinterpret_cast<us8*>(&As[r * LSTR + sc]) = *reinterpret_cast<us8*>(tmp);
            } else {
                *reinterpret_cast<bf16x8*>(&As[r * LSTR + sc]) =
                    *reinterpret_cast<const bf16x8*>(&A16[grow * K + k0 + sc]);
            }
        }
        if (btmode == 0) {
#pragma unroll
            for (int it = 0; it < 2; ++it) {
                int r = sr + it * 64;
                int gn = n0 + r; if (gn >= Nd) gn = Nd - 1;
                *reinterpret_cast<bf16x8*>(&Bs[r * LSTR + sc]) =
                    *reinterpret_cast<const bf16x8*>(&B16[(size_t)gn * K + k0 + sc]);
            }
        } else {
            const int kr = t >> 3;
            const int nc = (t & 7) * 16;
            if (fb) {
                const float* p = &B32[(size_t)(k0 + kr) * Nd + n0 + nc];
#pragma unroll
                for (int e = 0; e < 16; ++e) Bs[(nc + e) * LSTR + kr] = f2us(p[e]);
            } else {
                const unsigned short* p = &B16[(size_t)(k0 + kr) * Nd + n0 + nc];
#pragma unroll
                for (int e = 0; e < 16; ++e) Bs[(nc + e) * LSTR + kr] = p[e];
            }
        }
        __syncthreads();

        bf16x8 af[4], bfr[4];
#pragma unroll
        for (int i = 0; i < 4; ++i)
            af[i] = *reinterpret_cast<const bf16x8*>(&As[(wm + i * 16 + frow) * LSTR + koff]);
#pragma unroll
        for (int j = 0; j < 4; ++j)
            bfr[j] = *reinterpret_cast<const bf16x8*>(&Bs[(wn + j * 16 + frow) * LSTR + koff]);
#pragma unroll
        for (int i = 0; i < 4; ++i)
#pragma unroll
            for (int j = 0; j < 4; ++j)
                acc[i][j] = __builtin_amdgcn_mfma_f32_16x16x32_bf16(af[i], bfr[j], acc[i][j], 0, 0, 0);
        __syncthreads();
    }

    const int crow = (lane >> 4) * 4;
    const int ccol = lane & 15;
    unsigned short* C16 = (unsigned short*)Cout;
    float*          C32 = (float*)Cout;
#pragma unroll
    for (int i = 0; i < 4; ++i)
#pragma unroll
        for (int j = 0; j < 4; ++j) {
            int gn = n0 + wn + j * 16 + ccol;
            float bv = 0.0f;
            if (bias16) bv = fb ? bias32[gn] : us2f(bias16[gn]);
#pragma unroll
            for (int r = 0; r < 4; ++r) {
                int gm = m0 + wm + i * 16 + crow + r;
                if (gm < M) {
                    float v = acc[i][j][r] + bv;
                    if (fo) C32[(size_t)gm * Nd + gn] = v;
                    else    C16[(size_t)gm * Nd + gn] = f2us(v);
                }
            }
        }
}

// ---------------------------------------------------------------------------
// Window attention, MFMA version. Block = (window, head, bb), 4 waves.
// ---------------------------------------------------------------------------
#define AST 72    // bf16 tile stride (elements)
#define SST 65    // S f32 stride (elements)

__global__ __launch_bounds__(256) void win_attn(
    const unsigned short* __restrict__ qkv2,
    const unsigned short* __restrict__ m16, const float* __restrict__ m32,
    const int* __restrict__ flagp,
    unsigned short* __restrict__ xcat, int b0)
{
    __shared__ __align__(16) unsigned short qs[64 * AST];   // reused as ps
    __shared__ __align__(16) unsigned short ks[64 * AST];
    __shared__ __align__(16) unsigned short vsT[64 * AST];  // [d][key]
    __shared__ float S[64 * SST];
    __shared__ float tok[64];

    const int w  = blockIdx.x;
    const int h  = blockIdx.y;
    const int bb = blockIdx.z;
    const int b  = b0 + bb;
    const int hb = w >> 3, wb = w & 7;
    const int t  = threadIdx.x;
    const int f  = *flagp;
    const unsigned short* qkvb = qkv2 + (size_t)bb * NTOK * 2304;

#define POS(i) ((hb * 8 + ((i) >> 3)) * 64 + wb * 8 + ((i) & 7))

#pragma unroll
    for (int it = 0; it < 2; ++it) {
        int i = (t >> 3) + it * 32;
        int d = (t & 7) * 8;
        size_t row = (size_t)(1 + POS(i)) * 2304;
        bf16x8 qv = *reinterpret_cast<const bf16x8*>(&qkvb[row + 0    + h * 64 + d]);
        bf16x8 kv = *reinterpret_cast<const bf16x8*>(&qkvb[row + 768  + h * 64 + d]);
        us8    vv = *reinterpret_cast<const us8*>  (&qkvb[row + 1536 + h * 64 + d]);
        *reinterpret_cast<bf16x8*>(&qs[i * AST + d]) = qv;
        *reinterpret_cast<bf16x8*>(&ks[i * AST + d]) = kv;
#pragma unroll
        for (int e = 0; e < 8; ++e) vsT[(d + e) * AST + i] = vv[e];
    }
    if (t < 64) {
        size_t mi = ((size_t)b * HW_ + POS(t)) * C_;
        tok[t] = f ? m32[mi] : us2f(m16[mi]);
    }
    __syncthreads();

    const int wave = t >> 6;
    const int lane = t & 63;
    const int wm   = (wave >> 1) * 32;
    const int wn   = (wave & 1) * 32;
    const int frow = lane & 15;
    const int koff = (lane >> 4) * 8;
    const int crow = (lane >> 4) * 4;
    const int ccol = lane & 15;

    // ---- QK^T: S = Q @ K^T (wave tile 32x32, K=64) ----
    {
        f32x4 acc[2][2];
#pragma unroll
        for (int i = 0; i < 2; ++i)
#pragma unroll
            for (int j = 0; j < 2; ++j) acc[i][j] = (f32x4)0.0f;
#pragma unroll
        for (int kk = 0; kk < 64; kk += 32) {
            bf16x8 af[2], bfr[2];
#pragma unroll
            for (int i = 0; i < 2; ++i)
                af[i] = *reinterpret_cast<const bf16x8*>(&qs[(wm + i * 16 + frow) * AST + kk + koff]);
#pragma unroll
            for (int j = 0; j < 2; ++j)
                bfr[j] = *reinterpret_cast<const bf16x8*>(&ks[(wn + j * 16 + frow) * AST + kk + koff]);
#pragma unroll
            for (int i = 0; i < 2; ++i)
#pragma unroll
                for (int j = 0; j < 2; ++j)
                    acc[i][j] = __builtin_amdgcn_mfma_f32_16x16x32_bf16(af[i], bfr[j], acc[i][j], 0, 0, 0);
        }
#pragma unroll
        for (int i = 0; i < 2; ++i)
#pragma unroll
            for (int j = 0; j < 2; ++j)
#pragma unroll
                for (int r = 0; r < 4; ++r)
                    S[(wm + i * 16 + crow + r) * SST + wn + j * 16 + ccol] = acc[i][j][r];
    }
    __syncthreads();

    // ---- softmax: 4 lanes per row, 16 cols each ----
    {
        const int r = t >> 2;
        const int q = t & 3;
        const float tr = tok[r];
        float sv[16];
        float mx = -1e30f;
#pragma unroll
        for (int e = 0; e < 16; ++e) {
            int c = q * 16 + e;
            float s = S[r * SST + c] * 0.125f;
            if (tr * tok[c] == 0.0f) s = NEGV;
            sv[e] = s;
            mx = fmaxf(mx, s);
        }
        mx = fmaxf(mx, __shfl_xor(mx, 1));
        mx = fmaxf(mx, __shfl_xor(mx, 2));
        float sum = 0.f;
#pragma unroll
        for (int e = 0; e < 16; ++e) { sv[e] = __expf(sv[e] - mx); sum += sv[e]; }
        sum += __shfl_xor(sum, 1);
        sum += __shfl_xor(sum, 2);
        const float inv = 1.0f / sum;
        unsigned short* ps = qs;   // overlay (qs dead after QK^T)
        us8 o0, o1;
#pragma unroll
        for (int e = 0; e < 8; ++e) { o0[e] = f2us(sv[e] * inv); o1[e] = f2us(sv[8 + e] * inv); }
        *reinterpret_cast<us8*>(&ps[r * AST + q * 16])     = o0;
        *reinterpret_cast<us8*>(&ps[r * AST + q * 16 + 8]) = o1;
    }
    __syncthreads();

    // ---- PV: O = P @ V ----
    {
        const unsigned short* ps = qs;
        f32x4 acc[2][2];
#pragma unroll
        for (int i = 0; i < 2; ++i)
#pragma unroll
            for (int j = 0; j < 2; ++j) acc[i][j] = (f32x4)0.0f;
#pragma unroll
        for (int kk = 0; kk < 64; kk += 32) {
            bf16x8 af[2], bfr[2];
#pragma unroll
            for (int i = 0; i < 2; ++i)
                af[i] = *reinterpret_cast<const bf16x8*>(&ps[(wm + i * 16 + frow) * AST + kk + koff]);
#pragma unroll
            for (int j = 0; j < 2; ++j)
                bfr[j] = *reinterpret_cast<const bf16x8*>(&vsT[(wn + j * 16 + frow) * AST + kk + koff]);
#pragma unroll
            for (int i = 0; i < 2; ++i)
#pragma unroll
                for (int j = 0; j < 2; ++j)
                    acc[i][j] = __builtin_amdgcn_mfma_f32_16x16x32_bf16(af[i], bfr[j], acc[i][j], 0, 0, 0);
        }
#pragma unroll
        for (int i = 0; i < 2; ++i)
#pragma unroll
            for (int j = 0; j < 2; ++j)
#pragma unroll
                for (int r = 0; r < 4; ++r) {
                    int qrow = wm + i * 16 + crow + r;
                    int dcol = wn + j * 16 + ccol;
                    xcat[(size_t)(b * NTOK + 1 + POS(qrow)) * C_ + h * 64 + dcol] =
                        f2us(acc[i][j][r]);
                }
    }
#undef POS
}

// ---------------------------------------------------------------------------
// Cls attention, split-K partials (unchanged).
// ---------------------------------------------------------------------------
__global__ __launch_bounds__(256) void cls_part(
    const unsigned short* __restrict__ qkv2,
    const unsigned short* __restrict__ m16, const float* __restrict__ m32,
    const unsigned short* __restrict__ g16, const float* __restrict__ g32,
    const int* __restrict__ flagp,
    float* __restrict__ part,      // [B][NH][NSPLIT][68]
    int b0)
{
    __shared__ float q[64];
    __shared__ float e[256];
    __shared__ float red[256];
    __shared__ float osum[4][64];
    __shared__ float Mv, Sv;

    const int h  = blockIdx.x;
    const int sp = blockIdx.y;
    const int bb = blockIdx.z;
    const int b  = b0 + bb;
    const int t  = threadIdx.x;
    const int f  = *flagp;
    const unsigned short* qkvb = qkv2 + (size_t)bb * NTOK * 2304;

    if (t < 64) q[t] = us2f(qkvb[h * 64 + t]);   // row 0 = cls token
    __syncthreads();

    const int j = sp * 256 + t;                   // key 0..4095
    const unsigned short* krow = &qkvb[(size_t)(1 + j) * 2304 + 768 + h * 64];
    float s = 0.f;
#pragma unroll
    for (int dd = 0; dd < 8; ++dd) {
        us8 kv8 = *reinterpret_cast<const us8*>(&krow[dd * 8]);
#pragma unroll
        for (int ee = 0; ee < 8; ++ee) s += q[dd * 8 + ee] * us2f(kv8[ee]);
    }
    s *= 0.125f;
    {
        size_t mi = ((size_t)b * HW_ + j) * C_;
        size_t gi = ((size_t)b * NH_ + h) * HW_ + j;
        float tokj = f ? m32[mi] : us2f(m16[mi]);
        float gmj  = f ? g32[gi] : us2f(g16[gi]);
        if (tokj * gmj == 0.0f) s = NEGV;
    }

    red[t] = s; __syncthreads();
    for (int k2 = 128; k2 > 0; k2 >>= 1) { if (t < k2) red[t] = fmaxf(red[t], red[t + k2]); __syncthreads(); }
    const float m = red[0]; __syncthreads();

    float ev = __expf(s - m);
    e[t] = ev; red[t] = ev; __syncthreads();
    for (int k2 = 128; k2 > 0; k2 >>= 1) { if (t < k2) red[t] += red[t + k2]; __syncthreads(); }
    if (t == 0) { Mv = m; Sv = red[0]; }

    const int wv = t >> 6, l = t & 63;
    float accv = 0.f;
    const unsigned short* vbase =
        &qkvb[(size_t)(1 + sp * 256 + wv * 64) * 2304 + 1536 + h * 64 + l];
    for (int kk = 0; kk < 64; ++kk)
        accv += e[wv * 64 + kk] * us2f(vbase[(size_t)kk * 2304]);
    osum[wv][l] = accv;
    __syncthreads();

    const size_t pi = ((size_t)(b * NH_ + h) * NSPLIT + sp) * 68;
    if (t < 64)
        part[pi + t] = osum[0][t] + osum[1][t] + osum[2][t] + osum[3][t];
    if (t == 64 + 0) part[pi + 64] = Mv;
    if (t == 64 + 1) part[pi + 65] = Sv;
}

// ---------------------------------------------------------------------------
// Combine split partials (log-sum-exp merge) -> xcat cls rows (bf16)
// ---------------------------------------------------------------------------
__global__ __launch_bounds__(64) void cls_reduce(
    const float* __restrict__ part, unsigned short* __restrict__ xcat)
{
    const int h = blockIdx.x, b = blockIdx.y, t = threadIdx.x;
    const float* pb = &part[((size_t)(b * NH_ + h) * NSPLIT) * 68];
    float gm = -1e30f;
    for (int i = 0; i < NSPLIT; ++i) gm = fmaxf(gm, pb[i * 68 + 64]);
    float S = 0.f, acc = 0.f;
    for (int i = 0; i < NSPLIT; ++i) {
        float w = __expf(pb[i * 68 + 64] - gm);
        S   += pb[i * 68 + 65] * w;
        acc += pb[i * 68 + t]  * w;
    }
    xcat[(size_t)(b * NTOK) * C_ + h * 64 + t] = f2us(acc / S);
}

// ---------------------------------------------------------------------------
// v_cls GEMV + broadcast-add (unchanged).
// ---------------------------------------------------------------------------
__global__ __launch_bounds__(256) void add_vcls(
    const unsigned short* __restrict__ xcat, unsigned short* __restrict__ xcatc,
    const unsigned short* __restrict__ kv16, const float* __restrict__ kv32,
    const int* __restrict__ flagp)
{
    __shared__ float xr[768];
    __shared__ float psum[4][64];
    __shared__ float vc[64];

    const int blk = blockIdx.x;
    const int rsp = blockIdx.y;
    const int b   = blk / 12;
    const int c0  = (blk % 12) * 64;
    const int t   = threadIdx.x;
    const int f   = *flagp;

    for (int it = 0; it < 3; ++it) {
        int k = t + it * 256;
        xr[k] = us2f(xcat[(size_t)(b * NTOK) * C_ + k]);
    }
    __syncthreads();

    const int cc = t & 63, kq = t >> 6;
    float p = 0.f;
    for (int k = kq * 192; k < kq * 192 + 192; ++k) {
        size_t wi = (size_t)k * 1536 + 768 + c0 + cc;
        p += xr[k] * (f ? kv32[wi] : us2f(kv16[wi]));
    }
    psum[kq][cc] = p;
    __syncthreads();
    if (t < 64) vc[t] = psum[0][t] + psum[1][t] + psum[2][t] + psum[3][t];
    __syncthreads();

    const int ch8  = (t & 7) * 8;
    const int rsub = t >> 3;
    for (int it = 0; it < 32; ++it) {
        int row = rsp * 1024 + it * 32 + rsub;
        size_t off = (size_t)(b * NTOK + 1 + row) * C_ + c0 + ch8;
        us8 vv = *reinterpret_cast<const us8*>(&xcat[off]);
#pragma unroll
        for (int e2 = 0; e2 < 8; ++e2)
            vv[e2] = f2us(us2f(vv[e2]) + vc[ch8 + e2]);
        *reinterpret_cast<us8*>(&xcatc[off]) = vv;
    }
    if (rsp == 0 && t < 64)
        xcatc[(size_t)(b * NTOK) * C_ + c0 + t] = xcat[(size_t)(b * NTOK) * C_ + c0 + t];
}

// ---------------------------------------------------------------------------
// Workspace plan:
//   [0,128)                    flag
//   [128, 37,758,080)          qkv_2b   (2-batch slab, reused 4x)
//   [37,758,080, 41,297,024)   qkv_wT   (dead after last qkv GEMM)
//   [41,297,024, 41,714,816)   cls partials (dead after cls_reduce)
//   [128, 50,344,064)          xcatc    (written by add_vcls, after all above die)
//   [50,344,064, 51,523,712)   pwT      (proj_w^T bf16, survives to final GEMM)
// ---------------------------------------------------------------------------
extern "C" void kernel_launch(void* const* d_in, const int* in_sizes, int n_in,
                              void* d_out, int out_size, void* d_ws, size_t ws_size,
                              hipStream_t stream)
{
    const unsigned short* x16  = (const unsigned short*)d_in[0];
    const float*          x32  = (const float*)d_in[0];
    const unsigned short* m16  = (const unsigned short*)d_in[1];
    const float*          m32  = (const float*)d_in[1];
    const unsigned short* g16  = (const unsigned short*)d_in[2];
    const float*          g32  = (const float*)d_in[2];
    const unsigned short* qw16 = (const unsigned short*)d_in[3];
    const float*          qw32 = (const float*)d_in[3];
    const unsigned short* kv16 = (const unsigned short*)d_in[4];
    const float*          kv32 = (const float*)d_in[4];
    const unsigned short* pw16 = (const unsigned short*)d_in[5];
    const float*          pw32 = (const float*)d_in[5];
    const unsigned short* pb16 = (const unsigned short*)d_in[6];
    const float*          pb32 = (const float*)d_in[6];

    char* ws = (char*)d_ws;
    int*            flag   = (int*)ws;
    unsigned short* qkv_2b = (unsigned short*)(ws + 128);
    unsigned short* qkv_wT = (unsigned short*)(ws + 37758080);
    float*          part   = (float*)(ws + 41297024);
    unsigned short* xcatc  = (unsigned short*)(ws + 128);
    unsigned short* pwT    = (unsigned short*)(ws + 50344064);
    unsigned short* xcat   = (unsigned short*)d_out;

    const bool fastproj = (ws_size >= (size_t)51523712);

    detect_dtype<<<1, 256, 0, stream>>>((const unsigned int*)d_in[0], flag);
    transpose_w<<<(2304 * 768 + 255) / 256, 256, 0, stream>>>(
        qw16, qw32, flag, qkv_wT, 768, 2304);
    if (fastproj)
        transpose_w<<<(768 * 768 + 255) / 256, 256, 0, stream>>>(
            pw16, pw32, flag, pwT, 768, 768);

    for (int b0 = 0; b0 < B_; b0 += 2) {
        gemm_bt<<<dim3(18, 65), 256, 0, stream>>>(
            x16, x32, flag, qkv_wT,
            nullptr, nullptr, nullptr,
            qkv_2b, nullptr,
            2 * NTOK, 2304, 768, (long)b0 * NTOK);
        win_attn<<<dim3(64, 12, 2), 256, 0, stream>>>(qkv_2b, m16, m32, flag, xcat, b0);
        cls_part<<<dim3(12, NSPLIT, 2), 256, 0, stream>>>(
            qkv_2b, m16, m32, g16, g32, flag, part, b0);
    }

    cls_reduce<<<dim3(12, 8), 64, 0, stream>>>(part, xcat);
    add_vcls<<<dim3(96, 4), 256, 0, stream>>>(xcat, xcatc, kv16, kv32, flag);

    if (fastproj) {
        gemm_bt<<<dim3(6, 257), 256, 0, stream>>>(
            xcatc, nullptr, nullptr, pwT,
            pb16, pb32, flag,
            d_out, flag,
            MTOT, 768, 768, 0);
    } else {
        gemm_univ<<<dim3(6, 257), 256, 0, stream>>>(
            xcatc, nullptr, nullptr, pw16, pw32, flag, 1,
            pb16, pb32, d_out, flag,
            MTOT, 768, 768, 0);
    }
}

// Round 4
// 769.793 us; speedup vs baseline: 1.0524x; 1.0524x over previous
//
#include <hip/hip_runtime.h>

// Problem constants: B=8, C=768, NH=12, WS=8, NC=1, H=W=64
#define B_    8
#define C_    768
#define NH_   12
#define HW_   4096
#define NTOK  4097
#define MTOT  32776         // B_ * NTOK
#define NEGV  (-10000.0f)
#define NSPLIT 16

typedef __bf16 bf16x8 __attribute__((ext_vector_type(8)));
typedef float  f32x4  __attribute__((ext_vector_type(4)));
typedef unsigned short us8 __attribute__((ext_vector_type(8)));

// addrspace casts for global_load_lds
#define GLB(p) ((const __attribute__((address_space(1))) void*)(p))
#define LDS(p) ((__attribute__((address_space(3))) void*)(p))

__device__ __forceinline__ float us2f(unsigned short u) {
    unsigned int v = ((unsigned int)u) << 16;
    float f; __builtin_memcpy(&f, &v, 4);
    return f;
}
__device__ __forceinline__ unsigned short f2us(float f) {
    unsigned int v; __builtin_memcpy(&v, &f, 4);
    v += 0x7FFFu + ((v >> 16) & 1u);   // RNE
    return (unsigned short)(v >> 16);
}

// ---------------------------------------------------------------------------
// Runtime dtype detect (flag=1 -> fp32 inputs).
// ---------------------------------------------------------------------------
__global__ __launch_bounds__(256) void detect_dtype(
    const unsigned int* __restrict__ xw, int* __restrict__ flag)
{
    __shared__ int s[256];
    int t = threadIdx.x, cnt = 0;
    for (int i = t; i < 4096; i += 256) {
        unsigned e = (xw[i] >> 23) & 0xFFu;
        cnt += (e >= 64u && e <= 191u) ? 1 : 0;
    }
    s[t] = cnt; __syncthreads();
    for (int k = 128; k > 0; k >>= 1) { if (t < k) s[t] += s[t + k]; __syncthreads(); }
    if (t == 0) *flag = (s[0] > 2048) ? 1 : 0;
}

// ---------------------------------------------------------------------------
// Generic weight transpose: src (Kd x Nd, flag dtype) -> dst (Nd x Kd, bf16)
// ---------------------------------------------------------------------------
__global__ __launch_bounds__(256) void transpose_w(
    const unsigned short* __restrict__ s16, const float* __restrict__ s32,
    const int* __restrict__ flagp, unsigned short* __restrict__ dst,
    int Kd, int Nd)
{
    int o = blockIdx.x * 256 + threadIdx.x;
    if (o >= Kd * Nd) return;
    int n = o / Kd, k = o % Kd;
    dst[o] = (*flagp) ? f2us(s32[(size_t)k * Nd + n]) : s16[(size_t)k * Nd + n];
}

// ---------------------------------------------------------------------------
// Fast GEMM: 128x128 tile, BK=64, 4 waves, 16x16x32 MFMA, single-buffered
// (dbuf proven null r3). 12 barrier events per block instead of 24.
// LDS [128][64] bf16 tiles, linear, staged via global_load_lds dwordx4 with
// XOR-swizzle (catalog #21): linear dest + inverse-swizzled SOURCE column +
// swizzled read slot. slot ^= (row&7) spreads the 128-B rows across all 32
// banks (8-clk b128 floor).
// ---------------------------------------------------------------------------
__global__ __launch_bounds__(256) void gemm_bt(
    const unsigned short* __restrict__ A16, const float* __restrict__ A32,
    const int* __restrict__ aflagp,
    const unsigned short* __restrict__ BT,
    const unsigned short* __restrict__ bias16, const float* __restrict__ bias32,
    const int* __restrict__ bflagp,
    void* __restrict__ Cout, const int* __restrict__ oflagp,
    int M, int Nd, int K, long arow0)
{
    __shared__ __align__(16) unsigned short As[128 * 64];   // 16 KB
    __shared__ __align__(16) unsigned short Bs[128 * 64];   // 16 KB

    const int fa = aflagp ? *aflagp : 0;
    const int fb = bflagp ? *bflagp : 0;
    const int fo = oflagp ? *oflagp : 0;

    const int t    = threadIdx.x;
    const int m0   = blockIdx.y * 128;
    const int n0   = blockIdx.x * 128;
    const int wave = t >> 6;
    const int lane = t & 63;
    const int wm   = (wave >> 1) * 64;
    const int wn   = (wave & 1) * 64;
    const int frow = lane & 15;
    const int lsl  = lane >> 4;          // k-slot base within 32-wide half

    f32x4 acc[4][4];
#pragma unroll
    for (int i = 0; i < 4; ++i)
#pragma unroll
        for (int j = 0; j < 4; ++j) acc[i][j] = (f32x4)0.0f;

    // staging geometry (per 128x64 tile): thread t, chunk it in 0..3:
    //   dest row r = (t>>3) + it*32, dest slot = t&7 (8 elems = 16B)
    //   dest elem  = it*2048 + t*8   (linear)
    //   source col = ((t&7) ^ (r&7))*8  with r&7 == (t>>3)&7
    const int tr   = t >> 3;
    const int srcc = (((t & 7) ^ (tr & 7)) * 8);

    const float* aF[4];
    const unsigned short* aP[4];
    const unsigned short* bP[4];
#pragma unroll
    for (int it = 0; it < 4; ++it) {
        int ga = m0 + tr + it * 32; if (ga >= M)  ga = M - 1;
        int gb = n0 + tr + it * 32; if (gb >= Nd) gb = Nd - 1;
        aP[it] = A16 + (size_t)(arow0 + ga) * K + srcc;
        aF[it] = A32 + (size_t)(arow0 + ga) * K + srcc;
        bP[it] = BT  + (size_t)gb * K + srcc;
    }

    for (int k0 = 0; k0 < K; k0 += 64) {
        if (fa) {   // fp32 A fallback: register stage + convert (block-uniform)
#pragma unroll
            for (int it = 0; it < 4; ++it) {
                unsigned short tmp[8];
                const float* p = aF[it] + k0;
#pragma unroll
                for (int e = 0; e < 8; ++e) tmp[e] = f2us(p[e]);
                *reinterpret_cast<us8*>(&As[it * 2048 + t * 8]) = *reinterpret_cast<us8*>(tmp);
            }
        } else {
#pragma unroll
            for (int it = 0; it < 4; ++it)
                __builtin_amdgcn_global_load_lds(GLB(aP[it] + k0), LDS(&As[it * 2048 + t * 8]), 16, 0, 0);
        }
#pragma unroll
        for (int it = 0; it < 4; ++it)
            __builtin_amdgcn_global_load_lds(GLB(bP[it] + k0), LDS(&Bs[it * 2048 + t * 8]), 16, 0, 0);
        __syncthreads();

#pragma unroll
        for (int kk = 0; kk < 64; kk += 32) {
            const int ksl = (kk >> 3) + lsl;   // global k-slot 0..7
            bf16x8 af[4], bfr[4];
#pragma unroll
            for (int i = 0; i < 4; ++i) {
                int ra = wm + i * 16 + frow;
                af[i] = *reinterpret_cast<const bf16x8*>(&As[ra * 64 + ((ksl ^ (ra & 7)) << 3)]);
            }
#pragma unroll
            for (int j = 0; j < 4; ++j) {
                int rb = wn + j * 16 + frow;
                bfr[j] = *reinterpret_cast<const bf16x8*>(&Bs[rb * 64 + ((ksl ^ (rb & 7)) << 3)]);
            }
#pragma unroll
            for (int i = 0; i < 4; ++i)
#pragma unroll
                for (int j = 0; j < 4; ++j)
                    acc[i][j] = __builtin_amdgcn_mfma_f32_16x16x32_bf16(af[i], bfr[j], acc[i][j], 0, 0, 0);
        }
        __syncthreads();
    }

    const int crow = (lane >> 4) * 4;
    const int ccol = lane & 15;
    unsigned short* C16 = (unsigned short*)Cout;
    float*          C32 = (float*)Cout;
#pragma unroll
    for (int i = 0; i < 4; ++i)
#pragma unroll
        for (int j = 0; j < 4; ++j) {
            int gn = n0 + wn + j * 16 + ccol;
            float bv = 0.0f;
            if (bias16) bv = fb ? bias32[gn] : us2f(bias16[gn]);
#pragma unroll
            for (int r = 0; r < 4; ++r) {
                int gm = m0 + wm + i * 16 + crow + r;
                if (gm < M) {
                    float v = acc[i][j][r] + bv;
                    if (fo) C32[(size_t)gm * Nd + gn] = v;
                    else    C16[(size_t)gm * Nd + gn] = f2us(v);
                }
            }
        }
}

// ---------------------------------------------------------------------------
// Universal GEMM (fallback for proj when ws too small for pwT).
// ---------------------------------------------------------------------------
#define LSTR 40   // 32+8 pad; 80 B rows, 16B-aligned

__global__ __launch_bounds__(256) void gemm_univ(
    const unsigned short* __restrict__ A16, const float* __restrict__ A32,
    const int* __restrict__ aflagp,
    const unsigned short* __restrict__ B16, const float* __restrict__ B32,
    const int* __restrict__ bflagp, int btmode,
    const unsigned short* __restrict__ bias16, const float* __restrict__ bias32,
    void* __restrict__ Cout, const int* __restrict__ oflagp,
    int M, int Nd, int K, long arow0)
{
    __shared__ __align__(16) unsigned short As[128 * LSTR];
    __shared__ __align__(16) unsigned short Bs[128 * LSTR];

    const int fa = aflagp ? *aflagp : 0;
    const int fb = bflagp ? *bflagp : 0;
    const int fo = oflagp ? *oflagp : 0;

    const int t    = threadIdx.x;
    const int m0   = blockIdx.y * 128;
    const int n0   = blockIdx.x * 128;
    const int wave = t >> 6;
    const int lane = t & 63;
    const int wm   = (wave >> 1) * 64;
    const int wn   = (wave & 1) * 64;
    const int frow = lane & 15;
    const int koff = (lane >> 4) * 8;

    f32x4 acc[4][4];
#pragma unroll
    for (int i = 0; i < 4; ++i)
#pragma unroll
        for (int j = 0; j < 4; ++j) acc[i][j] = (f32x4)0.0f;

    const int sr = t >> 2;
    const int sc = (t & 3) * 8;

    for (int k0 = 0; k0 < K; k0 += 32) {
#pragma unroll
        for (int it = 0; it < 2; ++it) {
            int r = sr + it * 64;
            int gl = m0 + r; if (gl >= M) gl = M - 1;
            size_t grow = (size_t)(arow0 + gl);
            if (fa) {
                const float* p = &A32[grow * K + k0 + sc];
                unsigned short tmp[8];
#pragma unroll
                for (int e = 0; e < 8; ++e) tmp[e] = f2us(p[e]);
                *reinterpret_cast<us8*>(&As[r * LSTR + sc]) = *reinterpret_cast<us8*>(tmp);
            } else {
                *reinterpret_cast<bf16x8*>(&As[r * LSTR + sc]) =
                    *reinterpret_cast<const bf16x8*>(&A16[grow * K + k0 + sc]);
            }
        }
        if (btmode == 0) {
#pragma unroll
            for (int it = 0; it < 2; ++it) {
                int r = sr + it * 64;
                int gn = n0 + r; if (gn >= Nd) gn = Nd - 1;
                *reinterpret_cast<bf16x8*>(&Bs[r * LSTR + sc]) =
                    *reinterpret_cast<const bf16x8*>(&B16[(size_t)gn * K + k0 + sc]);
            }
        } else {
            const int kr = t >> 3;
            const int nc = (t & 7) * 16;
            if (fb) {
                const float* p = &B32[(size_t)(k0 + kr) * Nd + n0 + nc];
#pragma unroll
                for (int e = 0; e < 16; ++e) Bs[(nc + e) * LSTR + kr] = f2us(p[e]);
            } else {
                const unsigned short* p = &B16[(size_t)(k0 + kr) * Nd + n0 + nc];
#pragma unroll
                for (int e = 0; e < 16; ++e) Bs[(nc + e) * LSTR + kr] = p[e];
            }
        }
        __syncthreads();

        bf16x8 af[4], bfr[4];
#pragma unroll
        for (int i = 0; i < 4; ++i)
            af[i] = *reinterpret_cast<const bf16x8*>(&As[(wm + i * 16 + frow) * LSTR + koff]);
#pragma unroll
        for (int j = 0; j < 4; ++j)
            bfr[j] = *reinterpret_cast<const bf16x8*>(&Bs[(wn + j * 16 + frow) * LSTR + koff]);
#pragma unroll
        for (int i = 0; i < 4; ++i)
#pragma unroll
            for (int j = 0; j < 4; ++j)
                acc[i][j] = __builtin_amdgcn_mfma_f32_16x16x32_bf16(af[i], bfr[j], acc[i][j], 0, 0, 0);
        __syncthreads();
    }

    const int crow = (lane >> 4) * 4;
    const int ccol = lane & 15;
    unsigned short* C16 = (unsigned short*)Cout;
    float*          C32 = (float*)Cout;
#pragma unroll
    for (int i = 0; i < 4; ++i)
#pragma unroll
        for (int j = 0; j < 4; ++j) {
            int gn = n0 + wn + j * 16 + ccol;
            float bv = 0.0f;
            if (bias16) bv = fb ? bias32[gn] : us2f(bias16[gn]);
#pragma unroll
            for (int r = 0; r < 4; ++r) {
                int gm = m0 + wm + i * 16 + crow + r;
                if (gm < M) {
                    float v = acc[i][j][r] + bv;
                    if (fo) C32[(size_t)gm * Nd + gn] = v;
                    else    C16[(size_t)gm * Nd + gn] = f2us(v);
                }
            }
        }
}

// ---------------------------------------------------------------------------
// Window attention, MFMA version. Block = (window, head, bb), 4 waves.
// ---------------------------------------------------------------------------
#define AST 72    // bf16 tile stride (elements)
#define SST 65    // S f32 stride (elements)

__global__ __launch_bounds__(256) void win_attn(
    const unsigned short* __restrict__ qkv2,
    const unsigned short* __restrict__ m16, const float* __restrict__ m32,
    const int* __restrict__ flagp,
    unsigned short* __restrict__ xcat, int b0)
{
    __shared__ __align__(16) unsigned short qs[64 * AST];   // reused as ps
    __shared__ __align__(16) unsigned short ks[64 * AST];
    __shared__ __align__(16) unsigned short vsT[64 * AST];  // [d][key]
    __shared__ float S[64 * SST];
    __shared__ float tok[64];

    const int w  = blockIdx.x;
    const int h  = blockIdx.y;
    const int bb = blockIdx.z;
    const int b  = b0 + bb;
    const int hb = w >> 3, wb = w & 7;
    const int t  = threadIdx.x;
    const int f  = *flagp;
    const unsigned short* qkvb = qkv2 + (size_t)bb * NTOK * 2304;

#define POS(i) ((hb * 8 + ((i) >> 3)) * 64 + wb * 8 + ((i) & 7))

#pragma unroll
    for (int it = 0; it < 2; ++it) {
        int i = (t >> 3) + it * 32;
        int d = (t & 7) * 8;
        size_t row = (size_t)(1 + POS(i)) * 2304;
        bf16x8 qv = *reinterpret_cast<const bf16x8*>(&qkvb[row + 0    + h * 64 + d]);
        bf16x8 kv = *reinterpret_cast<const bf16x8*>(&qkvb[row + 768  + h * 64 + d]);
        us8    vv = *reinterpret_cast<const us8*>  (&qkvb[row + 1536 + h * 64 + d]);
        *reinterpret_cast<bf16x8*>(&qs[i * AST + d]) = qv;
        *reinterpret_cast<bf16x8*>(&ks[i * AST + d]) = kv;
#pragma unroll
        for (int e = 0; e < 8; ++e) vsT[(d + e) * AST + i] = vv[e];
    }
    if (t < 64) {
        size_t mi = ((size_t)b * HW_ + POS(t)) * C_;
        tok[t] = f ? m32[mi] : us2f(m16[mi]);
    }
    __syncthreads();

    const int wave = t >> 6;
    const int lane = t & 63;
    const int wm   = (wave >> 1) * 32;
    const int wn   = (wave & 1) * 32;
    const int frow = lane & 15;
    const int koff = (lane >> 4) * 8;
    const int crow = (lane >> 4) * 4;
    const int ccol = lane & 15;

    // ---- QK^T: S = Q @ K^T (wave tile 32x32, K=64) ----
    {
        f32x4 acc[2][2];
#pragma unroll
        for (int i = 0; i < 2; ++i)
#pragma unroll
            for (int j = 0; j < 2; ++j) acc[i][j] = (f32x4)0.0f;
#pragma unroll
        for (int kk = 0; kk < 64; kk += 32) {
            bf16x8 af[2], bfr[2];
#pragma unroll
            for (int i = 0; i < 2; ++i)
                af[i] = *reinterpret_cast<const bf16x8*>(&qs[(wm + i * 16 + frow) * AST + kk + koff]);
#pragma unroll
            for (int j = 0; j < 2; ++j)
                bfr[j] = *reinterpret_cast<const bf16x8*>(&ks[(wn + j * 16 + frow) * AST + kk + koff]);
#pragma unroll
            for (int i = 0; i < 2; ++i)
#pragma unroll
                for (int j = 0; j < 2; ++j)
                    acc[i][j] = __builtin_amdgcn_mfma_f32_16x16x32_bf16(af[i], bfr[j], acc[i][j], 0, 0, 0);
        }
#pragma unroll
        for (int i = 0; i < 2; ++i)
#pragma unroll
            for (int j = 0; j < 2; ++j)
#pragma unroll
                for (int r = 0; r < 4; ++r)
                    S[(wm + i * 16 + crow + r) * SST + wn + j * 16 + ccol] = acc[i][j][r];
    }
    __syncthreads();

    // ---- softmax: 4 lanes per row, 16 cols each ----
    {
        const int r = t >> 2;
        const int q = t & 3;
        const float tr = tok[r];
        float sv[16];
        float mx = -1e30f;
#pragma unroll
        for (int e = 0; e < 16; ++e) {
            int c = q * 16 + e;
            float s = S[r * SST + c] * 0.125f;
            if (tr * tok[c] == 0.0f) s = NEGV;
            sv[e] = s;
            mx = fmaxf(mx, s);
        }
        mx = fmaxf(mx, __shfl_xor(mx, 1));
        mx = fmaxf(mx, __shfl_xor(mx, 2));
        float sum = 0.f;
#pragma unroll
        for (int e = 0; e < 16; ++e) { sv[e] = __expf(sv[e] - mx); sum += sv[e]; }
        sum += __shfl_xor(sum, 1);
        sum += __shfl_xor(sum, 2);
        const float inv = 1.0f / sum;
        unsigned short* ps = qs;   // overlay (qs dead after QK^T)
        us8 o0, o1;
#pragma unroll
        for (int e = 0; e < 8; ++e) { o0[e] = f2us(sv[e] * inv); o1[e] = f2us(sv[8 + e] * inv); }
        *reinterpret_cast<us8*>(&ps[r * AST + q * 16])     = o0;
        *reinterpret_cast<us8*>(&ps[r * AST + q * 16 + 8]) = o1;
    }
    __syncthreads();

    // ---- PV: O = P @ V ----
    {
        const unsigned short* ps = qs;
        f32x4 acc[2][2];
#pragma unroll
        for (int i = 0; i < 2; ++i)
#pragma unroll
            for (int j = 0; j < 2; ++j) acc[i][j] = (f32x4)0.0f;
#pragma unroll
        for (int kk = 0; kk < 64; kk += 32) {
            bf16x8 af[2], bfr[2];
#pragma unroll
            for (int i = 0; i < 2; ++i)
                af[i] = *reinterpret_cast<const bf16x8*>(&ps[(wm + i * 16 + frow) * AST + kk + koff]);
#pragma unroll
            for (int j = 0; j < 2; ++j)
                bfr[j] = *reinterpret_cast<const bf16x8*>(&vsT[(wn + j * 16 + frow) * AST + kk + koff]);
#pragma unroll
            for (int i = 0; i < 2; ++i)
#pragma unroll
                for (int j = 0; j < 2; ++j)
                    acc[i][j] = __builtin_amdgcn_mfma_f32_16x16x32_bf16(af[i], bfr[j], acc[i][j], 0, 0, 0);
        }
#pragma unroll
        for (int i = 0; i < 2; ++i)
#pragma unroll
            for (int j = 0; j < 2; ++j)
#pragma unroll
                for (int r = 0; r < 4; ++r) {
                    int qrow = wm + i * 16 + crow + r;
                    int dcol = wn + j * 16 + ccol;
                    xcat[(size_t)(b * NTOK + 1 + POS(qrow)) * C_ + h * 64 + dcol] =
                        f2us(acc[i][j][r]);
                }
    }
#undef POS
}

// ---------------------------------------------------------------------------
// Cls attention, split-K partials (unchanged).
// ---------------------------------------------------------------------------
__global__ __launch_bounds__(256) void cls_part(
    const unsigned short* __restrict__ qkv2,
    const unsigned short* __restrict__ m16, const float* __restrict__ m32,
    const unsigned short* __restrict__ g16, const float* __restrict__ g32,
    const int* __restrict__ flagp,
    float* __restrict__ part,      // [B][NH][NSPLIT][68]
    int b0)
{
    __shared__ float q[64];
    __shared__ float e[256];
    __shared__ float red[256];
    __shared__ float osum[4][64];
    __shared__ float Mv, Sv;

    const int h  = blockIdx.x;
    const int sp = blockIdx.y;
    const int bb = blockIdx.z;
    const int b  = b0 + bb;
    const int t  = threadIdx.x;
    const int f  = *flagp;
    const unsigned short* qkvb = qkv2 + (size_t)bb * NTOK * 2304;

    if (t < 64) q[t] = us2f(qkvb[h * 64 + t]);   // row 0 = cls token
    __syncthreads();

    const int j = sp * 256 + t;                   // key 0..4095
    const unsigned short* krow = &qkvb[(size_t)(1 + j) * 2304 + 768 + h * 64];
    float s = 0.f;
#pragma unroll
    for (int dd = 0; dd < 8; ++dd) {
        us8 kv8 = *reinterpret_cast<const us8*>(&krow[dd * 8]);
#pragma unroll
        for (int ee = 0; ee < 8; ++ee) s += q[dd * 8 + ee] * us2f(kv8[ee]);
    }
    s *= 0.125f;
    {
        size_t mi = ((size_t)b * HW_ + j) * C_;
        size_t gi = ((size_t)b * NH_ + h) * HW_ + j;
        float tokj = f ? m32[mi] : us2f(m16[mi]);
        float gmj  = f ? g32[gi] : us2f(g16[gi]);
        if (tokj * gmj == 0.0f) s = NEGV;
    }

    red[t] = s; __syncthreads();
    for (int k2 = 128; k2 > 0; k2 >>= 1) { if (t < k2) red[t] = fmaxf(red[t], red[t + k2]); __syncthreads(); }
    const float m = red[0]; __syncthreads();

    float ev = __expf(s - m);
    e[t] = ev; red[t] = ev; __syncthreads();
    for (int k2 = 128; k2 > 0; k2 >>= 1) { if (t < k2) red[t] += red[t + k2]; __syncthreads(); }
    if (t == 0) { Mv = m; Sv = red[0]; }

    const int wv = t >> 6, l = t & 63;
    float accv = 0.f;
    const unsigned short* vbase =
        &qkvb[(size_t)(1 + sp * 256 + wv * 64) * 2304 + 1536 + h * 64 + l];
    for (int kk = 0; kk < 64; ++kk)
        accv += e[wv * 64 + kk] * us2f(vbase[(size_t)kk * 2304]);
    osum[wv][l] = accv;
    __syncthreads();

    const size_t pi = ((size_t)(b * NH_ + h) * NSPLIT + sp) * 68;
    if (t < 64)
        part[pi + t] = osum[0][t] + osum[1][t] + osum[2][t] + osum[3][t];
    if (t == 64 + 0) part[pi + 64] = Mv;
    if (t == 64 + 1) part[pi + 65] = Sv;
}

// ---------------------------------------------------------------------------
// Combine split partials (log-sum-exp merge) -> xcat cls rows (bf16)
// ---------------------------------------------------------------------------
__global__ __launch_bounds__(64) void cls_reduce(
    const float* __restrict__ part, unsigned short* __restrict__ xcat)
{
    const int h = blockIdx.x, b = blockIdx.y, t = threadIdx.x;
    const float* pb = &part[((size_t)(b * NH_ + h) * NSPLIT) * 68];
    float gm = -1e30f;
    for (int i = 0; i < NSPLIT; ++i) gm = fmaxf(gm, pb[i * 68 + 64]);
    float S = 0.f, acc = 0.f;
    for (int i = 0; i < NSPLIT; ++i) {
        float w = __expf(pb[i * 68 + 64] - gm);
        S   += pb[i * 68 + 65] * w;
        acc += pb[i * 68 + t]  * w;
    }
    xcat[(size_t)(b * NTOK) * C_ + h * 64 + t] = f2us(acc / S);
}

// ---------------------------------------------------------------------------
// v_cls GEMV + broadcast-add (unchanged).
// ---------------------------------------------------------------------------
__global__ __launch_bounds__(256) void add_vcls(
    const unsigned short* __restrict__ xcat, unsigned short* __restrict__ xcatc,
    const unsigned short* __restrict__ kv16, const float* __restrict__ kv32,
    const int* __restrict__ flagp)
{
    __shared__ float xr[768];
    __shared__ float psum[4][64];
    __shared__ float vc[64];

    const int blk = blockIdx.x;
    const int rsp = blockIdx.y;
    const int b   = blk / 12;
    const int c0  = (blk % 12) * 64;
    const int t   = threadIdx.x;
    const int f   = *flagp;

    for (int it = 0; it < 3; ++it) {
        int k = t + it * 256;
        xr[k] = us2f(xcat[(size_t)(b * NTOK) * C_ + k]);
    }
    __syncthreads();

    const int cc = t & 63, kq = t >> 6;
    float p = 0.f;
    for (int k = kq * 192; k < kq * 192 + 192; ++k) {
        size_t wi = (size_t)k * 1536 + 768 + c0 + cc;
        p += xr[k] * (f ? kv32[wi] : us2f(kv16[wi]));
    }
    psum[kq][cc] = p;
    __syncthreads();
    if (t < 64) vc[t] = psum[0][t] + psum[1][t] + psum[2][t] + psum[3][t];
    __syncthreads();

    const int ch8  = (t & 7) * 8;
    const int rsub = t >> 3;
    for (int it = 0; it < 32; ++it) {
        int row = rsp * 1024 + it * 32 + rsub;
        size_t off = (size_t)(b * NTOK + 1 + row) * C_ + c0 + ch8;
        us8 vv = *reinterpret_cast<const us8*>(&xcat[off]);
#pragma unroll
        for (int e2 = 0; e2 < 8; ++e2)
            vv[e2] = f2us(us2f(vv[e2]) + vc[ch8 + e2]);
        *reinterpret_cast<us8*>(&xcatc[off]) = vv;
    }
    if (rsp == 0 && t < 64)
        xcatc[(size_t)(b * NTOK) * C_ + c0 + t] = xcat[(size_t)(b * NTOK) * C_ + c0 + t];
}

// ---------------------------------------------------------------------------
// Workspace plans.
// Small-ws (proven safe, ws >= 51,523,712):
//   [0,128) flag | [128, 37,758,080) qkv_2b | [37,758,080, 41,297,024) qkv_wT
//   [41,297,024, 41,714,816) part | [128, 50,344,064) xcatc (after above die)
//   [50,344,064, 51,523,712) pwT
// Big-ws fused (ws >= 156,168,320):
//   [0,128) flag | [128, 151,031,936) qkv_full (all 8 batches)
//   [151,031,936, 154,570,880) qkv_wT | [154,570,880, 154,988,672) part
//   [154,988,672, 156,168,320) pwT | xcatc overlays [128, ...) after qkv dead
// ---------------------------------------------------------------------------
extern "C" void kernel_launch(void* const* d_in, const int* in_sizes, int n_in,
                              void* d_out, int out_size, void* d_ws, size_t ws_size,
                              hipStream_t stream)
{
    const unsigned short* x16  = (const unsigned short*)d_in[0];
    const float*          x32  = (const float*)d_in[0];
    const unsigned short* m16  = (const unsigned short*)d_in[1];
    const float*          m32  = (const float*)d_in[1];
    const unsigned short* g16  = (const unsigned short*)d_in[2];
    const float*          g32  = (const float*)d_in[2];
    const unsigned short* qw16 = (const unsigned short*)d_in[3];
    const float*          qw32 = (const float*)d_in[3];
    const unsigned short* kv16 = (const unsigned short*)d_in[4];
    const float*          kv32 = (const float*)d_in[4];
    const unsigned short* pw16 = (const unsigned short*)d_in[5];
    const float*          pw32 = (const float*)d_in[5];
    const unsigned short* pb16 = (const unsigned short*)d_in[6];
    const float*          pb32 = (const float*)d_in[6];

    char* ws = (char*)d_ws;
    int*            flag  = (int*)ws;
    unsigned short* xcatc = (unsigned short*)(ws + 128);
    unsigned short* xcat  = (unsigned short*)d_out;

    const bool fused = (ws_size >= (size_t)156168320);

    detect_dtype<<<1, 256, 0, stream>>>((const unsigned int*)d_in[0], flag);

    if (fused) {
        unsigned short* qkv_full = (unsigned short*)(ws + 128);
        unsigned short* qkv_wT   = (unsigned short*)(ws + 151031936);
        float*          part     = (float*)(ws + 154570880);
        unsigned short* pwT      = (unsigned short*)(ws + 154988672);

        transpose_w<<<(2304 * 768 + 255) / 256, 256, 0, stream>>>(
            qw16, qw32, flag, qkv_wT, 768, 2304);
        transpose_w<<<(768 * 768 + 255) / 256, 256, 0, stream>>>(
            pw16, pw32, flag, pwT, 768, 768);

        gemm_bt<<<dim3(18, 257), 256, 0, stream>>>(
            x16, x32, flag, qkv_wT,
            nullptr, nullptr, nullptr,
            qkv_full, nullptr,
            MTOT, 2304, 768, 0);
        win_attn<<<dim3(64, 12, 8), 256, 0, stream>>>(qkv_full, m16, m32, flag, xcat, 0);
        cls_part<<<dim3(12, NSPLIT, 8), 256, 0, stream>>>(
            qkv_full, m16, m32, g16, g32, flag, part, 0);

        cls_reduce<<<dim3(12, 8), 64, 0, stream>>>(part, xcat);
        add_vcls<<<dim3(96, 4), 256, 0, stream>>>(xcat, xcatc, kv16, kv32, flag);

        gemm_bt<<<dim3(6, 257), 256, 0, stream>>>(
            xcatc, nullptr, nullptr, pwT,
            pb16, pb32, flag,
            d_out, flag,
            MTOT, 768, 768, 0);
        return;
    }

    unsigned short* qkv_2b = (unsigned short*)(ws + 128);
    unsigned short* qkv_wT = (unsigned short*)(ws + 37758080);
    float*          part   = (float*)(ws + 41297024);
    unsigned short* pwT    = (unsigned short*)(ws + 50344064);
    const bool fastproj = (ws_size >= (size_t)51523712);

    transpose_w<<<(2304 * 768 + 255) / 256, 256, 0, stream>>>(
        qw16, qw32, flag, qkv_wT, 768, 2304);
    if (fastproj)
        transpose_w<<<(768 * 768 + 255) / 256, 256, 0, stream>>>(
            pw16, pw32, flag, pwT, 768, 768);

    for (int b0 = 0; b0 < B_; b0 += 2) {
        gemm_bt<<<dim3(18, 65), 256, 0, stream>>>(
            x16, x32, flag, qkv_wT,
            nullptr, nullptr, nullptr,
            qkv_2b, nullptr,
            2 * NTOK, 2304, 768, (long)b0 * NTOK);
        win_attn<<<dim3(64, 12, 2), 256, 0, stream>>>(qkv_2b, m16, m32, flag, xcat, b0);
        cls_part<<<dim3(12, NSPLIT, 2), 256, 0, stream>>>(
            qkv_2b, m16, m32, g16, g32, flag, part, b0);
    }

    cls_reduce<<<dim3(12, 8), 64, 0, stream>>>(part, xcat);
    add_vcls<<<dim3(96, 4), 256, 0, stream>>>(xcat, xcatc, kv16, kv32, flag);

    if (fastproj) {
        gemm_bt<<<dim3(6, 257), 256, 0, stream>>>(
            xcatc, nullptr, nullptr, pwT,
            pb16, pb32, flag,
            d_out, flag,
            MTOT, 768, 768, 0);
    } else {
        gemm_univ<<<dim3(6, 257), 256, 0, stream>>>(
            xcatc, nullptr, nullptr, pw16, pw32, flag, 1,
            pb16, pb32, d_out, flag,
            MTOT, 768, 768, 0);
    }
}

// Round 5
// 750.717 us; speedup vs baseline: 1.0792x; 1.0254x over previous
//
#include <hip/hip_runtime.h>

// Problem constants: B=8, C=768, NH=12, WS=8, NC=1, H=W=64
#define B_    8
#define C_    768
#define NH_   12
#define HW_   4096
#define NTOK  4097
#define MTOT  32776         // B_ * NTOK
#define NEGV  (-10000.0f)
#define NSPLIT 16

typedef __bf16 bf16x8 __attribute__((ext_vector_type(8)));
typedef float  f32x4  __attribute__((ext_vector_type(4)));
typedef unsigned short us8 __attribute__((ext_vector_type(8)));

// addrspace casts for global_load_lds
#define GLB(p) ((const __attribute__((address_space(1))) void*)(p))
#define LDS(p) ((__attribute__((address_space(3))) void*)(p))

__device__ __forceinline__ float us2f(unsigned short u) {
    unsigned int v = ((unsigned int)u) << 16;
    float f; __builtin_memcpy(&f, &v, 4);
    return f;
}
__device__ __forceinline__ unsigned short f2us(float f) {
    unsigned int v; __builtin_memcpy(&v, &f, 4);
    v += 0x7FFFu + ((v >> 16) & 1u);   // RNE
    return (unsigned short)(v >> 16);
}

// ---------------------------------------------------------------------------
// Runtime dtype detect (flag=1 -> fp32 inputs).
// ---------------------------------------------------------------------------
__global__ __launch_bounds__(256) void detect_dtype(
    const unsigned int* __restrict__ xw, int* __restrict__ flag)
{
    __shared__ int s[256];
    int t = threadIdx.x, cnt = 0;
    for (int i = t; i < 4096; i += 256) {
        unsigned e = (xw[i] >> 23) & 0xFFu;
        cnt += (e >= 64u && e <= 191u) ? 1 : 0;
    }
    s[t] = cnt; __syncthreads();
    for (int k = 128; k > 0; k >>= 1) { if (t < k) s[t] += s[t + k]; __syncthreads(); }
    if (t == 0) *flag = (s[0] > 2048) ? 1 : 0;
}

// ---------------------------------------------------------------------------
// Generic weight transpose: src (Kd x Nd, flag dtype) -> dst (Nd x Kd, bf16)
// ---------------------------------------------------------------------------
__global__ __launch_bounds__(256) void transpose_w(
    const unsigned short* __restrict__ s16, const float* __restrict__ s32,
    const int* __restrict__ flagp, unsigned short* __restrict__ dst,
    int Kd, int Nd)
{
    int o = blockIdx.x * 256 + threadIdx.x;
    if (o >= Kd * Nd) return;
    int n = o / Kd, k = o % Kd;
    dst[o] = (*flagp) ? f2us(s32[(size_t)k * Nd + n]) : s16[(size_t)k * Nd + n];
}

// ---------------------------------------------------------------------------
// Fast GEMM: 128x128 tile, BK=64, 4 waves, 16x16x32 MFMA, single-buffered.
// LDS XOR-swizzled (bank conflicts = 0, r4 verified).
// NEW r5: XCD-aware bijective chunked blockIdx swizzle (T1/m204): each XCD
// owns a contiguous chunk of row-major (m,n) tile space, so A-panels are
// fetched once (18 sharers co-located) and the B panel stays L2-resident
// per XCD. Fixes the 8x A-overfetch seen in r4 (FETCH 464 MB vs 54 MB ideal).
// ---------------------------------------------------------------------------
__global__ __launch_bounds__(256) void gemm_bt(
    const unsigned short* __restrict__ A16, const float* __restrict__ A32,
    const int* __restrict__ aflagp,
    const unsigned short* __restrict__ BT,
    const unsigned short* __restrict__ bias16, const float* __restrict__ bias32,
    const int* __restrict__ bflagp,
    void* __restrict__ Cout, const int* __restrict__ oflagp,
    int M, int Nd, int K, long arow0)
{
    __shared__ __align__(16) unsigned short As[128 * 64];   // 16 KB
    __shared__ __align__(16) unsigned short Bs[128 * 64];   // 16 KB

    const int fa = aflagp ? *aflagp : 0;
    const int fb = bflagp ? *bflagp : 0;
    const int fo = oflagp ? *oflagp : 0;

    const int t    = threadIdx.x;

    // ---- XCD-aware bijective chunked swizzle (m204) ----
    const int nbx = gridDim.x;
    const int nwg = nbx * gridDim.y;
    const int lin = blockIdx.y * nbx + blockIdx.x;
    const int q   = nwg >> 3, r = nwg & 7;
    const int xcd = lin & 7, loc = lin >> 3;
    const int wg  = (xcd < r ? xcd * (q + 1) : r * (q + 1) + (xcd - r) * q) + loc;
    const int m0  = (wg / nbx) * 128;
    const int n0  = (wg % nbx) * 128;

    const int wave = t >> 6;
    const int lane = t & 63;
    const int wm   = (wave >> 1) * 64;
    const int wn   = (wave & 1) * 64;
    const int frow = lane & 15;
    const int lsl  = lane >> 4;          // k-slot base within 32-wide half

    f32x4 acc[4][4];
#pragma unroll
    for (int i = 0; i < 4; ++i)
#pragma unroll
        for (int j = 0; j < 4; ++j) acc[i][j] = (f32x4)0.0f;

    // staging geometry (per 128x64 tile): thread t, chunk it in 0..3:
    //   dest row r = (t>>3) + it*32, dest slot = t&7 (8 elems = 16B)
    //   dest elem  = it*2048 + t*8   (linear)
    //   source col = ((t&7) ^ (r&7))*8  with r&7 == (t>>3)&7
    const int tr   = t >> 3;
    const int srcc = (((t & 7) ^ (tr & 7)) * 8);

    const float* aF[4];
    const unsigned short* aP[4];
    const unsigned short* bP[4];
#pragma unroll
    for (int it = 0; it < 4; ++it) {
        int ga = m0 + tr + it * 32; if (ga >= M)  ga = M - 1;
        int gb = n0 + tr + it * 32; if (gb >= Nd) gb = Nd - 1;
        aP[it] = A16 + (size_t)(arow0 + ga) * K + srcc;
        aF[it] = A32 + (size_t)(arow0 + ga) * K + srcc;
        bP[it] = BT  + (size_t)gb * K + srcc;
    }

    for (int k0 = 0; k0 < K; k0 += 64) {
        if (fa) {   // fp32 A fallback: register stage + convert (block-uniform)
#pragma unroll
            for (int it = 0; it < 4; ++it) {
                unsigned short tmp[8];
                const float* p = aF[it] + k0;
#pragma unroll
                for (int e = 0; e < 8; ++e) tmp[e] = f2us(p[e]);
                *reinterpret_cast<us8*>(&As[it * 2048 + t * 8]) = *reinterpret_cast<us8*>(tmp);
            }
        } else {
#pragma unroll
            for (int it = 0; it < 4; ++it)
                __builtin_amdgcn_global_load_lds(GLB(aP[it] + k0), LDS(&As[it * 2048 + t * 8]), 16, 0, 0);
        }
#pragma unroll
        for (int it = 0; it < 4; ++it)
            __builtin_amdgcn_global_load_lds(GLB(bP[it] + k0), LDS(&Bs[it * 2048 + t * 8]), 16, 0, 0);
        __syncthreads();

#pragma unroll
        for (int kk = 0; kk < 64; kk += 32) {
            const int ksl = (kk >> 3) + lsl;   // global k-slot 0..7
            bf16x8 af[4], bfr[4];
#pragma unroll
            for (int i = 0; i < 4; ++i) {
                int ra = wm + i * 16 + frow;
                af[i] = *reinterpret_cast<const bf16x8*>(&As[ra * 64 + ((ksl ^ (ra & 7)) << 3)]);
            }
#pragma unroll
            for (int j = 0; j < 4; ++j) {
                int rb = wn + j * 16 + frow;
                bfr[j] = *reinterpret_cast<const bf16x8*>(&Bs[rb * 64 + ((ksl ^ (rb & 7)) << 3)]);
            }
#pragma unroll
            for (int i = 0; i < 4; ++i)
#pragma unroll
                for (int j = 0; j < 4; ++j)
                    acc[i][j] = __builtin_amdgcn_mfma_f32_16x16x32_bf16(af[i], bfr[j], acc[i][j], 0, 0, 0);
        }
        __syncthreads();
    }

    const int crow = (lane >> 4) * 4;
    const int ccol = lane & 15;
    unsigned short* C16 = (unsigned short*)Cout;
    float*          C32 = (float*)Cout;
#pragma unroll
    for (int i = 0; i < 4; ++i)
#pragma unroll
        for (int j = 0; j < 4; ++j) {
            int gn = n0 + wn + j * 16 + ccol;
            float bv = 0.0f;
            if (bias16) bv = fb ? bias32[gn] : us2f(bias16[gn]);
#pragma unroll
            for (int r2 = 0; r2 < 4; ++r2) {
                int gm = m0 + wm + i * 16 + crow + r2;
                if (gm < M) {
                    float v = acc[i][j][r2] + bv;
                    if (fo) C32[(size_t)gm * Nd + gn] = v;
                    else    C16[(size_t)gm * Nd + gn] = f2us(v);
                }
            }
        }
}

// ---------------------------------------------------------------------------
// Universal GEMM (fallback for proj when ws too small for pwT).
// ---------------------------------------------------------------------------
#define LSTR 40   // 32+8 pad; 80 B rows, 16B-aligned

__global__ __launch_bounds__(256) void gemm_univ(
    const unsigned short* __restrict__ A16, const float* __restrict__ A32,
    const int* __restrict__ aflagp,
    const unsigned short* __restrict__ B16, const float* __restrict__ B32,
    const int* __restrict__ bflagp, int btmode,
    const unsigned short* __restrict__ bias16, const float* __restrict__ bias32,
    void* __restrict__ Cout, const int* __restrict__ oflagp,
    int M, int Nd, int K, long arow0)
{
    __shared__ __align__(16) unsigned short As[128 * LSTR];
    __shared__ __align__(16) unsigned short Bs[128 * LSTR];

    const int fa = aflagp ? *aflagp : 0;
    const int fb = bflagp ? *bflagp : 0;
    const int fo = oflagp ? *oflagp : 0;

    const int t    = threadIdx.x;
    const int m0   = blockIdx.y * 128;
    const int n0   = blockIdx.x * 128;
    const int wave = t >> 6;
    const int lane = t & 63;
    const int wm   = (wave >> 1) * 64;
    const int wn   = (wave & 1) * 64;
    const int frow = lane & 15;
    const int koff = (lane >> 4) * 8;

    f32x4 acc[4][4];
#pragma unroll
    for (int i = 0; i < 4; ++i)
#pragma unroll
        for (int j = 0; j < 4; ++j) acc[i][j] = (f32x4)0.0f;

    const int sr = t >> 2;
    const int sc = (t & 3) * 8;

    for (int k0 = 0; k0 < K; k0 += 32) {
#pragma unroll
        for (int it = 0; it < 2; ++it) {
            int r = sr + it * 64;
            int gl = m0 + r; if (gl >= M) gl = M - 1;
            size_t grow = (size_t)(arow0 + gl);
            if (fa) {
                const float* p = &A32[grow * K + k0 + sc];
                unsigned short tmp[8];
#pragma unroll
                for (int e = 0; e < 8; ++e) tmp[e] = f2us(p[e]);
                *reinterpret_cast<us8*>(&As[r * LSTR + sc]) = *reinterpret_cast<us8*>(tmp);
            } else {
                *reinterpret_cast<bf16x8*>(&As[r * LSTR + sc]) =
                    *reinterpret_cast<const bf16x8*>(&A16[grow * K + k0 + sc]);
            }
        }
        if (btmode == 0) {
#pragma unroll
            for (int it = 0; it < 2; ++it) {
                int r = sr + it * 64;
                int gn = n0 + r; if (gn >= Nd) gn = Nd - 1;
                *reinterpret_cast<bf16x8*>(&Bs[r * LSTR + sc]) =
                    *reinterpret_cast<const bf16x8*>(&B16[(size_t)gn * K + k0 + sc]);
            }
        } else {
            const int kr = t >> 3;
            const int nc = (t & 7) * 16;
            if (fb) {
                const float* p = &B32[(size_t)(k0 + kr) * Nd + n0 + nc];
#pragma unroll
                for (int e = 0; e < 16; ++e) Bs[(nc + e) * LSTR + kr] = f2us(p[e]);
            } else {
                const unsigned short* p = &B16[(size_t)(k0 + kr) * Nd + n0 + nc];
#pragma unroll
                for (int e = 0; e < 16; ++e) Bs[(nc + e) * LSTR + kr] = p[e];
            }
        }
        __syncthreads();

        bf16x8 af[4], bfr[4];
#pragma unroll
        for (int i = 0; i < 4; ++i)
            af[i] = *reinterpret_cast<const bf16x8*>(&As[(wm + i * 16 + frow) * LSTR + koff]);
#pragma unroll
        for (int j = 0; j < 4; ++j)
            bfr[j] = *reinterpret_cast<const bf16x8*>(&Bs[(wn + j * 16 + frow) * LSTR + koff]);
#pragma unroll
        for (int i = 0; i < 4; ++i)
#pragma unroll
            for (int j = 0; j < 4; ++j)
                acc[i][j] = __builtin_amdgcn_mfma_f32_16x16x32_bf16(af[i], bfr[j], acc[i][j], 0, 0, 0);
        __syncthreads();
    }

    const int crow = (lane >> 4) * 4;
    const int ccol = lane & 15;
    unsigned short* C16 = (unsigned short*)Cout;
    float*          C32 = (float*)Cout;
#pragma unroll
    for (int i = 0; i < 4; ++i)
#pragma unroll
        for (int j = 0; j < 4; ++j) {
            int gn = n0 + wn + j * 16 + ccol;
            float bv = 0.0f;
            if (bias16) bv = fb ? bias32[gn] : us2f(bias16[gn]);
#pragma unroll
            for (int r = 0; r < 4; ++r) {
                int gm = m0 + wm + i * 16 + crow + r;
                if (gm < M) {
                    float v = acc[i][j][r] + bv;
                    if (fo) C32[(size_t)gm * Nd + gn] = v;
                    else    C16[(size_t)gm * Nd + gn] = f2us(v);
                }
            }
        }
}

// ---------------------------------------------------------------------------
// Window attention, MFMA version. Block = (window, head, bb), 4 waves.
// ---------------------------------------------------------------------------
#define AST 72    // bf16 tile stride (elements)
#define SST 65    // S f32 stride (elements)

__global__ __launch_bounds__(256) void win_attn(
    const unsigned short* __restrict__ qkv2,
    const unsigned short* __restrict__ m16, const float* __restrict__ m32,
    const int* __restrict__ flagp,
    unsigned short* __restrict__ xcat, int b0)
{
    __shared__ __align__(16) unsigned short qs[64 * AST];   // reused as ps
    __shared__ __align__(16) unsigned short ks[64 * AST];
    __shared__ __align__(16) unsigned short vsT[64 * AST];  // [d][key]
    __shared__ float S[64 * SST];
    __shared__ float tok[64];

    const int w  = blockIdx.x;
    const int h  = blockIdx.y;
    const int bb = blockIdx.z;
    const int b  = b0 + bb;
    const int hb = w >> 3, wb = w & 7;
    const int t  = threadIdx.x;
    const int f  = *flagp;
    const unsigned short* qkvb = qkv2 + (size_t)bb * NTOK * 2304;

#define POS(i) ((hb * 8 + ((i) >> 3)) * 64 + wb * 8 + ((i) & 7))

#pragma unroll
    for (int it = 0; it < 2; ++it) {
        int i = (t >> 3) + it * 32;
        int d = (t & 7) * 8;
        size_t row = (size_t)(1 + POS(i)) * 2304;
        bf16x8 qv = *reinterpret_cast<const bf16x8*>(&qkvb[row + 0    + h * 64 + d]);
        bf16x8 kv = *reinterpret_cast<const bf16x8*>(&qkvb[row + 768  + h * 64 + d]);
        us8    vv = *reinterpret_cast<const us8*>  (&qkvb[row + 1536 + h * 64 + d]);
        *reinterpret_cast<bf16x8*>(&qs[i * AST + d]) = qv;
        *reinterpret_cast<bf16x8*>(&ks[i * AST + d]) = kv;
#pragma unroll
        for (int e = 0; e < 8; ++e) vsT[(d + e) * AST + i] = vv[e];
    }
    if (t < 64) {
        size_t mi = ((size_t)b * HW_ + POS(t)) * C_;
        tok[t] = f ? m32[mi] : us2f(m16[mi]);
    }
    __syncthreads();

    const int wave = t >> 6;
    const int lane = t & 63;
    const int wm   = (wave >> 1) * 32;
    const int wn   = (wave & 1) * 32;
    const int frow = lane & 15;
    const int koff = (lane >> 4) * 8;
    const int crow = (lane >> 4) * 4;
    const int ccol = lane & 15;

    // ---- QK^T: S = Q @ K^T (wave tile 32x32, K=64) ----
    {
        f32x4 acc[2][2];
#pragma unroll
        for (int i = 0; i < 2; ++i)
#pragma unroll
            for (int j = 0; j < 2; ++j) acc[i][j] = (f32x4)0.0f;
#pragma unroll
        for (int kk = 0; kk < 64; kk += 32) {
            bf16x8 af[2], bfr[2];
#pragma unroll
            for (int i = 0; i < 2; ++i)
                af[i] = *reinterpret_cast<const bf16x8*>(&qs[(wm + i * 16 + frow) * AST + kk + koff]);
#pragma unroll
            for (int j = 0; j < 2; ++j)
                bfr[j] = *reinterpret_cast<const bf16x8*>(&ks[(wn + j * 16 + frow) * AST + kk + koff]);
#pragma unroll
            for (int i = 0; i < 2; ++i)
#pragma unroll
                for (int j = 0; j < 2; ++j)
                    acc[i][j] = __builtin_amdgcn_mfma_f32_16x16x32_bf16(af[i], bfr[j], acc[i][j], 0, 0, 0);
        }
#pragma unroll
        for (int i = 0; i < 2; ++i)
#pragma unroll
            for (int j = 0; j < 2; ++j)
#pragma unroll
                for (int r = 0; r < 4; ++r)
                    S[(wm + i * 16 + crow + r) * SST + wn + j * 16 + ccol] = acc[i][j][r];
    }
    __syncthreads();

    // ---- softmax: 4 lanes per row, 16 cols each ----
    {
        const int r = t >> 2;
        const int q = t & 3;
        const float tr = tok[r];
        float sv[16];
        float mx = -1e30f;
#pragma unroll
        for (int e = 0; e < 16; ++e) {
            int c = q * 16 + e;
            float s = S[r * SST + c] * 0.125f;
            if (tr * tok[c] == 0.0f) s = NEGV;
            sv[e] = s;
            mx = fmaxf(mx, s);
        }
        mx = fmaxf(mx, __shfl_xor(mx, 1));
        mx = fmaxf(mx, __shfl_xor(mx, 2));
        float sum = 0.f;
#pragma unroll
        for (int e = 0; e < 16; ++e) { sv[e] = __expf(sv[e] - mx); sum += sv[e]; }
        sum += __shfl_xor(sum, 1);
        sum += __shfl_xor(sum, 2);
        const float inv = 1.0f / sum;
        unsigned short* ps = qs;   // overlay (qs dead after QK^T)
        us8 o0, o1;
#pragma unroll
        for (int e = 0; e < 8; ++e) { o0[e] = f2us(sv[e] * inv); o1[e] = f2us(sv[8 + e] * inv); }
        *reinterpret_cast<us8*>(&ps[r * AST + q * 16])     = o0;
        *reinterpret_cast<us8*>(&ps[r * AST + q * 16 + 8]) = o1;
    }
    __syncthreads();

    // ---- PV: O = P @ V ----
    {
        const unsigned short* ps = qs;
        f32x4 acc[2][2];
#pragma unroll
        for (int i = 0; i < 2; ++i)
#pragma unroll
            for (int j = 0; j < 2; ++j) acc[i][j] = (f32x4)0.0f;
#pragma unroll
        for (int kk = 0; kk < 64; kk += 32) {
            bf16x8 af[2], bfr[2];
#pragma unroll
            for (int i = 0; i < 2; ++i)
                af[i] = *reinterpret_cast<const bf16x8*>(&ps[(wm + i * 16 + frow) * AST + kk + koff]);
#pragma unroll
            for (int j = 0; j < 2; ++j)
                bfr[j] = *reinterpret_cast<const bf16x8*>(&vsT[(wn + j * 16 + frow) * AST + kk + koff]);
#pragma unroll
            for (int i = 0; i < 2; ++i)
#pragma unroll
                for (int j = 0; j < 2; ++j)
                    acc[i][j] = __builtin_amdgcn_mfma_f32_16x16x32_bf16(af[i], bfr[j], acc[i][j], 0, 0, 0);
        }
#pragma unroll
        for (int i = 0; i < 2; ++i)
#pragma unroll
            for (int j = 0; j < 2; ++j)
#pragma unroll
                for (int r = 0; r < 4; ++r) {
                    int qrow = wm + i * 16 + crow + r;
                    int dcol = wn + j * 16 + ccol;
                    xcat[(size_t)(b * NTOK + 1 + POS(qrow)) * C_ + h * 64 + dcol] =
                        f2us(acc[i][j][r]);
                }
    }
#undef POS
}

// ---------------------------------------------------------------------------
// Cls attention, split-K partials (unchanged).
// ---------------------------------------------------------------------------
__global__ __launch_bounds__(256) void cls_part(
    const unsigned short* __restrict__ qkv2,
    const unsigned short* __restrict__ m16, const float* __restrict__ m32,
    const unsigned short* __restrict__ g16, const float* __restrict__ g32,
    const int* __restrict__ flagp,
    float* __restrict__ part,      // [B][NH][NSPLIT][68]
    int b0)
{
    __shared__ float q[64];
    __shared__ float e[256];
    __shared__ float red[256];
    __shared__ float osum[4][64];
    __shared__ float Mv, Sv;

    const int h  = blockIdx.x;
    const int sp = blockIdx.y;
    const int bb = blockIdx.z;
    const int b  = b0 + bb;
    const int t  = threadIdx.x;
    const int f  = *flagp;
    const unsigned short* qkvb = qkv2 + (size_t)bb * NTOK * 2304;

    if (t < 64) q[t] = us2f(qkvb[h * 64 + t]);   // row 0 = cls token
    __syncthreads();

    const int j = sp * 256 + t;                   // key 0..4095
    const unsigned short* krow = &qkvb[(size_t)(1 + j) * 2304 + 768 + h * 64];
    float s = 0.f;
#pragma unroll
    for (int dd = 0; dd < 8; ++dd) {
        us8 kv8 = *reinterpret_cast<const us8*>(&krow[dd * 8]);
#pragma unroll
        for (int ee = 0; ee < 8; ++ee) s += q[dd * 8 + ee] * us2f(kv8[ee]);
    }
    s *= 0.125f;
    {
        size_t mi = ((size_t)b * HW_ + j) * C_;
        size_t gi = ((size_t)b * NH_ + h) * HW_ + j;
        float tokj = f ? m32[mi] : us2f(m16[mi]);
        float gmj  = f ? g32[gi] : us2f(g16[gi]);
        if (tokj * gmj == 0.0f) s = NEGV;
    }

    red[t] = s; __syncthreads();
    for (int k2 = 128; k2 > 0; k2 >>= 1) { if (t < k2) red[t] = fmaxf(red[t], red[t + k2]); __syncthreads(); }
    const float m = red[0]; __syncthreads();

    float ev = __expf(s - m);
    e[t] = ev; red[t] = ev; __syncthreads();
    for (int k2 = 128; k2 > 0; k2 >>= 1) { if (t < k2) red[t] += red[t + k2]; __syncthreads(); }
    if (t == 0) { Mv = m; Sv = red[0]; }

    const int wv = t >> 6, l = t & 63;
    float accv = 0.f;
    const unsigned short* vbase =
        &qkvb[(size_t)(1 + sp * 256 + wv * 64) * 2304 + 1536 + h * 64 + l];
    for (int kk = 0; kk < 64; ++kk)
        accv += e[wv * 64 + kk] * us2f(vbase[(size_t)kk * 2304]);
    osum[wv][l] = accv;
    __syncthreads();

    const size_t pi = ((size_t)(b * NH_ + h) * NSPLIT + sp) * 68;
    if (t < 64)
        part[pi + t] = osum[0][t] + osum[1][t] + osum[2][t] + osum[3][t];
    if (t == 64 + 0) part[pi + 64] = Mv;
    if (t == 64 + 1) part[pi + 65] = Sv;
}

// ---------------------------------------------------------------------------
// Combine split partials (log-sum-exp merge) -> xcat cls rows (bf16)
// ---------------------------------------------------------------------------
__global__ __launch_bounds__(64) void cls_reduce(
    const float* __restrict__ part, unsigned short* __restrict__ xcat)
{
    const int h = blockIdx.x, b = blockIdx.y, t = threadIdx.x;
    const float* pb = &part[((size_t)(b * NH_ + h) * NSPLIT) * 68];
    float gm = -1e30f;
    for (int i = 0; i < NSPLIT; ++i) gm = fmaxf(gm, pb[i * 68 + 64]);
    float S = 0.f, acc = 0.f;
    for (int i = 0; i < NSPLIT; ++i) {
        float w = __expf(pb[i * 68 + 64] - gm);
        S   += pb[i * 68 + 65] * w;
        acc += pb[i * 68 + t]  * w;
    }
    xcat[(size_t)(b * NTOK) * C_ + h * 64 + t] = f2us(acc / S);
}

// ---------------------------------------------------------------------------
// v_cls GEMV + broadcast-add (unchanged).
// ---------------------------------------------------------------------------
__global__ __launch_bounds__(256) void add_vcls(
    const unsigned short* __restrict__ xcat, unsigned short* __restrict__ xcatc,
    const unsigned short* __restrict__ kv16, const float* __restrict__ kv32,
    const int* __restrict__ flagp)
{
    __shared__ float xr[768];
    __shared__ float psum[4][64];
    __shared__ float vc[64];

    const int blk = blockIdx.x;
    const int rsp = blockIdx.y;
    const int b   = blk / 12;
    const int c0  = (blk % 12) * 64;
    const int t   = threadIdx.x;
    const int f   = *flagp;

    for (int it = 0; it < 3; ++it) {
        int k = t + it * 256;
        xr[k] = us2f(xcat[(size_t)(b * NTOK) * C_ + k]);
    }
    __syncthreads();

    const int cc = t & 63, kq = t >> 6;
    float p = 0.f;
    for (int k = kq * 192; k < kq * 192 + 192; ++k) {
        size_t wi = (size_t)k * 1536 + 768 + c0 + cc;
        p += xr[k] * (f ? kv32[wi] : us2f(kv16[wi]));
    }
    psum[kq][cc] = p;
    __syncthreads();
    if (t < 64) vc[t] = psum[0][t] + psum[1][t] + psum[2][t] + psum[3][t];
    __syncthreads();

    const int ch8  = (t & 7) * 8;
    const int rsub = t >> 3;
    for (int it = 0; it < 32; ++it) {
        int row = rsp * 1024 + it * 32 + rsub;
        size_t off = (size_t)(b * NTOK + 1 + row) * C_ + c0 + ch8;
        us8 vv = *reinterpret_cast<const us8*>(&xcat[off]);
#pragma unroll
        for (int e2 = 0; e2 < 8; ++e2)
            vv[e2] = f2us(us2f(vv[e2]) + vc[ch8 + e2]);
        *reinterpret_cast<us8*>(&xcatc[off]) = vv;
    }
    if (rsp == 0 && t < 64)
        xcatc[(size_t)(b * NTOK) * C_ + c0 + t] = xcat[(size_t)(b * NTOK) * C_ + c0 + t];
}

// ---------------------------------------------------------------------------
// Workspace plans.
// Small-ws (proven safe, ws >= 51,523,712):
//   [0,128) flag | [128, 37,758,080) qkv_2b | [37,758,080, 41,297,024) qkv_wT
//   [41,297,024, 41,714,816) part | [128, 50,344,064) xcatc (after above die)
//   [50,344,064, 51,523,712) pwT
// Big-ws fused (ws >= 156,168,320):
//   [0,128) flag | [128, 151,031,936) qkv_full (all 8 batches)
//   [151,031,936, 154,570,880) qkv_wT | [154,570,880, 154,988,672) part
//   [154,988,672, 156,168,320) pwT | xcatc overlays [128, ...) after qkv dead
// ---------------------------------------------------------------------------
extern "C" void kernel_launch(void* const* d_in, const int* in_sizes, int n_in,
                              void* d_out, int out_size, void* d_ws, size_t ws_size,
                              hipStream_t stream)
{
    const unsigned short* x16  = (const unsigned short*)d_in[0];
    const float*          x32  = (const float*)d_in[0];
    const unsigned short* m16  = (const unsigned short*)d_in[1];
    const float*          m32  = (const float*)d_in[1];
    const unsigned short* g16  = (const unsigned short*)d_in[2];
    const float*          g32  = (const float*)d_in[2];
    const unsigned short* qw16 = (const unsigned short*)d_in[3];
    const float*          qw32 = (const float*)d_in[3];
    const unsigned short* kv16 = (const unsigned short*)d_in[4];
    const float*          kv32 = (const float*)d_in[4];
    const unsigned short* pw16 = (const unsigned short*)d_in[5];
    const float*          pw32 = (const float*)d_in[5];
    const unsigned short* pb16 = (const unsigned short*)d_in[6];
    const float*          pb32 = (const float*)d_in[6];

    char* ws = (char*)d_ws;
    int*            flag  = (int*)ws;
    unsigned short* xcatc = (unsigned short*)(ws + 128);
    unsigned short* xcat  = (unsigned short*)d_out;

    const bool fused = (ws_size >= (size_t)156168320);

    detect_dtype<<<1, 256, 0, stream>>>((const unsigned int*)d_in[0], flag);

    if (fused) {
        unsigned short* qkv_full = (unsigned short*)(ws + 128);
        unsigned short* qkv_wT   = (unsigned short*)(ws + 151031936);
        float*          part     = (float*)(ws + 154570880);
        unsigned short* pwT      = (unsigned short*)(ws + 154988672);

        transpose_w<<<(2304 * 768 + 255) / 256, 256, 0, stream>>>(
            qw16, qw32, flag, qkv_wT, 768, 2304);
        transpose_w<<<(768 * 768 + 255) / 256, 256, 0, stream>>>(
            pw16, pw32, flag, pwT, 768, 768);

        gemm_bt<<<dim3(18, 257), 256, 0, stream>>>(
            x16, x32, flag, qkv_wT,
            nullptr, nullptr, nullptr,
            qkv_full, nullptr,
            MTOT, 2304, 768, 0);
        win_attn<<<dim3(64, 12, 8), 256, 0, stream>>>(qkv_full, m16, m32, flag, xcat, 0);
        cls_part<<<dim3(12, NSPLIT, 8), 256, 0, stream>>>(
            qkv_full, m16, m32, g16, g32, flag, part, 0);

        cls_reduce<<<dim3(12, 8), 64, 0, stream>>>(part, xcat);
        add_vcls<<<dim3(96, 4), 256, 0, stream>>>(xcat, xcatc, kv16, kv32, flag);

        gemm_bt<<<dim3(6, 257), 256, 0, stream>>>(
            xcatc, nullptr, nullptr, pwT,
            pb16, pb32, flag,
            d_out, flag,
            MTOT, 768, 768, 0);
        return;
    }

    unsigned short* qkv_2b = (unsigned short*)(ws + 128);
    unsigned short* qkv_wT = (unsigned short*)(ws + 37758080);
    float*          part   = (float*)(ws + 41297024);
    unsigned short* pwT    = (unsigned short*)(ws + 50344064);
    const bool fastproj = (ws_size >= (size_t)51523712);

    transpose_w<<<(2304 * 768 + 255) / 256, 256, 0, stream>>>(
        qw16, qw32, flag, qkv_wT, 768, 2304);
    if (fastproj)
        transpose_w<<<(768 * 768 + 255) / 256, 256, 0, stream>>>(
            pw16, pw32, flag, pwT, 768, 768);

    for (int b0 = 0; b0 < B_; b0 += 2) {
        gemm_bt<<<dim3(18, 65), 256, 0, stream>>>(
            x16, x32, flag, qkv_wT,
            nullptr, nullptr, nullptr,
            qkv_2b, nullptr,
            2 * NTOK, 2304, 768, (long)b0 * NTOK);
        win_attn<<<dim3(64, 12, 2), 256, 0, stream>>>(qkv_2b, m16, m32, flag, xcat, b0);
        cls_part<<<dim3(12, NSPLIT, 2), 256, 0, stream>>>(
            qkv_2b, m16, m32, g16, g32, flag, part, b0);
    }

    cls_reduce<<<dim3(12, 8), 64, 0, stream>>>(part, xcat);
    add_vcls<<<dim3(96, 4), 256, 0, stream>>>(xcat, xcatc, kv16, kv32, flag);

    if (fastproj) {
        gemm_bt<<<dim3(6, 257), 256, 0, stream>>>(
            xcatc, nullptr, nullptr, pwT,
            pb16, pb32, flag,
            d_out, flag,
            MTOT, 768, 768, 0);
    } else {
        gemm_univ<<<dim3(6, 257), 256, 0, stream>>>(
            xcatc, nullptr, nullptr, pw16, pw32, flag, 1,
            pb16, pb32, d_out, flag,
            MTOT, 768, 768, 0);
    }
}

// Round 6
// 747.193 us; speedup vs baseline: 1.0843x; 1.0047x over previous
//
#include <hip/hip_runtime.h>

// Problem constants: B=8, C=768, NH=12, WS=8, NC=1, H=W=64
#define B_    8
#define C_    768
#define NH_   12
#define HW_   4096
#define NTOK  4097
#define MTOT  32776         // B_ * NTOK
#define NEGV  (-10000.0f)
#define NSPLIT 16

typedef __bf16 bf16x8 __attribute__((ext_vector_type(8)));
typedef float  f32x4  __attribute__((ext_vector_type(4)));
typedef unsigned short us8 __attribute__((ext_vector_type(8)));

// addrspace casts for global_load_lds
#define GLB(p) ((const __attribute__((address_space(1))) void*)(p))
#define LDS(p) ((__attribute__((address_space(3))) void*)(p))

__device__ __forceinline__ float us2f(unsigned short u) {
    unsigned int v = ((unsigned int)u) << 16;
    float f; __builtin_memcpy(&f, &v, 4);
    return f;
}
__device__ __forceinline__ unsigned short f2us(float f) {
    unsigned int v; __builtin_memcpy(&v, &f, 4);
    v += 0x7FFFu + ((v >> 16) & 1u);   // RNE
    return (unsigned short)(v >> 16);
}

// ---------------------------------------------------------------------------
// Runtime dtype detect (flag=1 -> fp32 inputs).
// ---------------------------------------------------------------------------
__global__ __launch_bounds__(256) void detect_dtype(
    const unsigned int* __restrict__ xw, int* __restrict__ flag)
{
    __shared__ int s[256];
    int t = threadIdx.x, cnt = 0;
    for (int i = t; i < 4096; i += 256) {
        unsigned e = (xw[i] >> 23) & 0xFFu;
        cnt += (e >= 64u && e <= 191u) ? 1 : 0;
    }
    s[t] = cnt; __syncthreads();
    for (int k = 128; k > 0; k >>= 1) { if (t < k) s[t] += s[t + k]; __syncthreads(); }
    if (t == 0) *flag = (s[0] > 2048) ? 1 : 0;
}

// ---------------------------------------------------------------------------
// Generic weight transpose: src (Kd x Nd, flag dtype) -> dst (Nd x Kd, bf16)
// ---------------------------------------------------------------------------
__global__ __launch_bounds__(256) void transpose_w(
    const unsigned short* __restrict__ s16, const float* __restrict__ s32,
    const int* __restrict__ flagp, unsigned short* __restrict__ dst,
    int Kd, int Nd)
{
    int o = blockIdx.x * 256 + threadIdx.x;
    if (o >= Kd * Nd) return;
    int n = o / Kd, k = o % Kd;
    dst[o] = (*flagp) ? f2us(s32[(size_t)k * Nd + n]) : s16[(size_t)k * Nd + n];
}

// ---------------------------------------------------------------------------
// Fast GEMM: 128x128 tile, BK=64, 4 waves, 16x16x32 MFMA.
// r4: XOR-swizzled LDS (bank conflicts = 0). r5: XCD-aware bijective chunked
// blockIdx swizzle (FETCH 464->187 MB, verified).
// r6: counted-vmcnt double-buffer (T4). Raw s_barrier + s_waitcnt vmcnt(8):
// next tile's 8 global_load_lds stay IN FLIGHT across the barrier; their
// latency hides under the current tile's 32-MFMA compute. The only wait is
// "oldest 8 of 16", which had a full compute phase to land. This is the piece
// __syncthreads (vmcnt(0) drain) structurally forbids — r3's null.
// ---------------------------------------------------------------------------
__global__ __launch_bounds__(256) void gemm_bt(
    const unsigned short* __restrict__ A16, const float* __restrict__ A32,
    const int* __restrict__ aflagp,
    const unsigned short* __restrict__ BT,
    const unsigned short* __restrict__ bias16, const float* __restrict__ bias32,
    const int* __restrict__ bflagp,
    void* __restrict__ Cout, const int* __restrict__ oflagp,
    int M, int Nd, int K, long arow0)
{
    __shared__ __align__(16) unsigned short As[2][128 * 64];   // 2 x 16 KB
    __shared__ __align__(16) unsigned short Bs[2][128 * 64];   // 2 x 16 KB

    const int fa = aflagp ? *aflagp : 0;
    const int fb = bflagp ? *bflagp : 0;
    const int fo = oflagp ? *oflagp : 0;

    const int t    = threadIdx.x;

    // ---- XCD-aware bijective chunked swizzle (m204) ----
    const int nbx = gridDim.x;
    const int nwg = nbx * gridDim.y;
    const int lin = blockIdx.y * nbx + blockIdx.x;
    const int q   = nwg >> 3, r = nwg & 7;
    const int xcd = lin & 7, loc = lin >> 3;
    const int wg  = (xcd < r ? xcd * (q + 1) : r * (q + 1) + (xcd - r) * q) + loc;
    const int m0  = (wg / nbx) * 128;
    const int n0  = (wg % nbx) * 128;

    const int wave = t >> 6;
    const int lane = t & 63;
    const int wm   = (wave >> 1) * 64;
    const int wn   = (wave & 1) * 64;
    const int frow = lane & 15;
    const int lsl  = lane >> 4;          // k-slot base within 32-wide half

    f32x4 acc[4][4];
#pragma unroll
    for (int i = 0; i < 4; ++i)
#pragma unroll
        for (int j = 0; j < 4; ++j) acc[i][j] = (f32x4)0.0f;

    // staging geometry (per 128x64 tile): thread t, chunk it in 0..3:
    //   dest row r = (t>>3) + it*32, dest slot = t&7 (8 elems = 16B)
    //   dest elem  = it*2048 + t*8   (linear)
    //   source col = ((t&7) ^ (r&7))*8  with r&7 == (t>>3)&7
    const int tr   = t >> 3;
    const int srcc = (((t & 7) ^ (tr & 7)) * 8);

    const float* aF[4];
    const unsigned short* aP[4];
    const unsigned short* bP[4];
#pragma unroll
    for (int it = 0; it < 4; ++it) {
        int ga = m0 + tr + it * 32; if (ga >= M)  ga = M - 1;
        int gb = n0 + tr + it * 32; if (gb >= Nd) gb = Nd - 1;
        aP[it] = A16 + (size_t)(arow0 + ga) * K + srcc;
        aF[it] = A32 + (size_t)(arow0 + ga) * K + srcc;
        bP[it] = BT  + (size_t)gb * K + srcc;
    }

#define STAGE_TILE(buf, koff_)                                                              \
    do {                                                                                    \
        _Pragma("unroll")                                                                   \
        for (int it = 0; it < 4; ++it) {                                                    \
            __builtin_amdgcn_global_load_lds(GLB(aP[it] + (koff_)),                         \
                LDS(&As[(buf)][it * 2048 + t * 8]), 16, 0, 0);                              \
            __builtin_amdgcn_global_load_lds(GLB(bP[it] + (koff_)),                         \
                LDS(&Bs[(buf)][it * 2048 + t * 8]), 16, 0, 0);                              \
        }                                                                                   \
    } while (0)

#define COMPUTE_TILE(buf)                                                                   \
    do {                                                                                    \
        _Pragma("unroll")                                                                   \
        for (int kk = 0; kk < 64; kk += 32) {                                               \
            const int ksl = (kk >> 3) + lsl;                                                \
            bf16x8 af[4], bfr[4];                                                           \
            _Pragma("unroll")                                                               \
            for (int i = 0; i < 4; ++i) {                                                   \
                int ra = wm + i * 16 + frow;                                                \
                af[i] = *reinterpret_cast<const bf16x8*>(                                   \
                    &As[(buf)][ra * 64 + ((ksl ^ (ra & 7)) << 3)]);                         \
            }                                                                               \
            _Pragma("unroll")                                                               \
            for (int j = 0; j < 4; ++j) {                                                   \
                int rb = wn + j * 16 + frow;                                                \
                bfr[j] = *reinterpret_cast<const bf16x8*>(                                  \
                    &Bs[(buf)][rb * 64 + ((ksl ^ (rb & 7)) << 3)]);                         \
            }                                                                               \
            _Pragma("unroll")                                                               \
            for (int i = 0; i < 4; ++i)                                                     \
                _Pragma("unroll")                                                           \
                for (int j = 0; j < 4; ++j)                                                 \
                    acc[i][j] = __builtin_amdgcn_mfma_f32_16x16x32_bf16(                    \
                        af[i], bfr[j], acc[i][j], 0, 0, 0);                                 \
        }                                                                                   \
    } while (0)

    if (!fa) {
        const int NT = K >> 6;   // 12 for K=768 (both call sites); NT >= 2 assumed
        // prologue: T0 -> buf0, T1 -> buf1 (16 loads in flight/wave)
        STAGE_TILE(0, 0);
        STAGE_TILE(1, 64);
        asm volatile("s_waitcnt vmcnt(8)" ::: "memory");   // T0 landed (mine)
        __builtin_amdgcn_s_barrier();                      // T0 landed (all waves)

        int cur = 0;
        for (int kt = 0; kt < NT; ++kt) {
            COMPUTE_TILE(cur);                   // tile kt; own ds_reads drained by
                                                 // compiler lgkmcnt before MFMA use
            __builtin_amdgcn_s_barrier();        // all waves done READING buf[cur]
            if (kt + 2 < NT) {
                const int nk = (kt + 2) << 6;
                STAGE_TILE(cur, nk);             // overwrite just-freed buffer
                asm volatile("s_waitcnt vmcnt(8)" ::: "memory");  // tile kt+1 landed
            } else {
                asm volatile("s_waitcnt vmcnt(0)" ::: "memory");  // drain tail
            }
            __builtin_amdgcn_s_barrier();        // tile kt+1 landed (all waves)
            cur ^= 1;
        }
    } else {
        // ---- legacy single-buffer path (fp32 A fallback) ----
        for (int k0 = 0; k0 < K; k0 += 64) {
#pragma unroll
            for (int it = 0; it < 4; ++it) {
                unsigned short tmp[8];
                const float* p = aF[it] + k0;
#pragma unroll
                for (int e = 0; e < 8; ++e) tmp[e] = f2us(p[e]);
                *reinterpret_cast<us8*>(&As[0][it * 2048 + t * 8]) = *reinterpret_cast<us8*>(tmp);
            }
#pragma unroll
            for (int it = 0; it < 4; ++it)
                __builtin_amdgcn_global_load_lds(GLB(bP[it] + k0), LDS(&Bs[0][it * 2048 + t * 8]), 16, 0, 0);
            __syncthreads();
            COMPUTE_TILE(0);
            __syncthreads();
        }
    }

#undef STAGE_TILE
#undef COMPUTE_TILE

    const int crow = (lane >> 4) * 4;
    const int ccol = lane & 15;
    unsigned short* C16 = (unsigned short*)Cout;
    float*          C32 = (float*)Cout;
#pragma unroll
    for (int i = 0; i < 4; ++i)
#pragma unroll
        for (int j = 0; j < 4; ++j) {
            int gn = n0 + wn + j * 16 + ccol;
            float bv = 0.0f;
            if (bias16) bv = fb ? bias32[gn] : us2f(bias16[gn]);
#pragma unroll
            for (int r2 = 0; r2 < 4; ++r2) {
                int gm = m0 + wm + i * 16 + crow + r2;
                if (gm < M) {
                    float v = acc[i][j][r2] + bv;
                    if (fo) C32[(size_t)gm * Nd + gn] = v;
                    else    C16[(size_t)gm * Nd + gn] = f2us(v);
                }
            }
        }
}

// ---------------------------------------------------------------------------
// Universal GEMM (fallback for proj when ws too small for pwT).
// ---------------------------------------------------------------------------
#define LSTR 40   // 32+8 pad; 80 B rows, 16B-aligned

__global__ __launch_bounds__(256) void gemm_univ(
    const unsigned short* __restrict__ A16, const float* __restrict__ A32,
    const int* __restrict__ aflagp,
    const unsigned short* __restrict__ B16, const float* __restrict__ B32,
    const int* __restrict__ bflagp, int btmode,
    const unsigned short* __restrict__ bias16, const float* __restrict__ bias32,
    void* __restrict__ Cout, const int* __restrict__ oflagp,
    int M, int Nd, int K, long arow0)
{
    __shared__ __align__(16) unsigned short As[128 * LSTR];
    __shared__ __align__(16) unsigned short Bs[128 * LSTR];

    const int fa = aflagp ? *aflagp : 0;
    const int fb = bflagp ? *bflagp : 0;
    const int fo = oflagp ? *oflagp : 0;

    const int t    = threadIdx.x;
    const int m0   = blockIdx.y * 128;
    const int n0   = blockIdx.x * 128;
    const int wave = t >> 6;
    const int lane = t & 63;
    const int wm   = (wave >> 1) * 64;
    const int wn   = (wave & 1) * 64;
    const int frow = lane & 15;
    const int koff = (lane >> 4) * 8;

    f32x4 acc[4][4];
#pragma unroll
    for (int i = 0; i < 4; ++i)
#pragma unroll
        for (int j = 0; j < 4; ++j) acc[i][j] = (f32x4)0.0f;

    const int sr = t >> 2;
    const int sc = (t & 3) * 8;

    for (int k0 = 0; k0 < K; k0 += 32) {
#pragma unroll
        for (int it = 0; it < 2; ++it) {
            int r = sr + it * 64;
            int gl = m0 + r; if (gl >= M) gl = M - 1;
            size_t grow = (size_t)(arow0 + gl);
            if (fa) {
                const float* p = &A32[grow * K + k0 + sc];
                unsigned short tmp[8];
#pragma unroll
                for (int e = 0; e < 8; ++e) tmp[e] = f2us(p[e]);
                *reinterpret_cast<us8*>(&As[r * LSTR + sc]) = *reinterpret_cast<us8*>(tmp);
            } else {
                *reinterpret_cast<bf16x8*>(&As[r * LSTR + sc]) =
                    *reinterpret_cast<const bf16x8*>(&A16[grow * K + k0 + sc]);
            }
        }
        if (btmode == 0) {
#pragma unroll
            for (int it = 0; it < 2; ++it) {
                int r = sr + it * 64;
                int gn = n0 + r; if (gn >= Nd) gn = Nd - 1;
                *reinterpret_cast<bf16x8*>(&Bs[r * LSTR + sc]) =
                    *reinterpret_cast<const bf16x8*>(&B16[(size_t)gn * K + k0 + sc]);
            }
        } else {
            const int kr = t >> 3;
            const int nc = (t & 7) * 16;
            if (fb) {
                const float* p = &B32[(size_t)(k0 + kr) * Nd + n0 + nc];
#pragma unroll
                for (int e = 0; e < 16; ++e) Bs[(nc + e) * LSTR + kr] = f2us(p[e]);
            } else {
                const unsigned short* p = &B16[(size_t)(k0 + kr) * Nd + n0 + nc];
#pragma unroll
                for (int e = 0; e < 16; ++e) Bs[(nc + e) * LSTR + kr] = p[e];
            }
        }
        __syncthreads();

        bf16x8 af[4], bfr[4];
#pragma unroll
        for (int i = 0; i < 4; ++i)
            af[i] = *reinterpret_cast<const bf16x8*>(&As[(wm + i * 16 + frow) * LSTR + koff]);
#pragma unroll
        for (int j = 0; j < 4; ++j)
            bfr[j] = *reinterpret_cast<const bf16x8*>(&Bs[(wn + j * 16 + frow) * LSTR + koff]);
#pragma unroll
        for (int i = 0; i < 4; ++i)
#pragma unroll
            for (int j = 0; j < 4; ++j)
                acc[i][j] = __builtin_amdgcn_mfma_f32_16x16x32_bf16(af[i], bfr[j], acc[i][j], 0, 0, 0);
        __syncthreads();
    }

    const int crow = (lane >> 4) * 4;
    const int ccol = lane & 15;
    unsigned short* C16 = (unsigned short*)Cout;
    float*          C32 = (float*)Cout;
#pragma unroll
    for (int i = 0; i < 4; ++i)
#pragma unroll
        for (int j = 0; j < 4; ++j) {
            int gn = n0 + wn + j * 16 + ccol;
            float bv = 0.0f;
            if (bias16) bv = fb ? bias32[gn] : us2f(bias16[gn]);
#pragma unroll
            for (int r = 0; r < 4; ++r) {
                int gm = m0 + wm + i * 16 + crow + r;
                if (gm < M) {
                    float v = acc[i][j][r] + bv;
                    if (fo) C32[(size_t)gm * Nd + gn] = v;
                    else    C16[(size_t)gm * Nd + gn] = f2us(v);
                }
            }
        }
}

// ---------------------------------------------------------------------------
// Window attention, MFMA version. Block = (window, head, bb), 4 waves.
// ---------------------------------------------------------------------------
#define AST 72    // bf16 tile stride (elements)
#define SST 65    // S f32 stride (elements)

__global__ __launch_bounds__(256) void win_attn(
    const unsigned short* __restrict__ qkv2,
    const unsigned short* __restrict__ m16, const float* __restrict__ m32,
    const int* __restrict__ flagp,
    unsigned short* __restrict__ xcat, int b0)
{
    __shared__ __align__(16) unsigned short qs[64 * AST];   // reused as ps
    __shared__ __align__(16) unsigned short ks[64 * AST];
    __shared__ __align__(16) unsigned short vsT[64 * AST];  // [d][key]
    __shared__ float S[64 * SST];
    __shared__ float tok[64];

    const int w  = blockIdx.x;
    const int h  = blockIdx.y;
    const int bb = blockIdx.z;
    const int b  = b0 + bb;
    const int hb = w >> 3, wb = w & 7;
    const int t  = threadIdx.x;
    const int f  = *flagp;
    const unsigned short* qkvb = qkv2 + (size_t)bb * NTOK * 2304;

#define POS(i) ((hb * 8 + ((i) >> 3)) * 64 + wb * 8 + ((i) & 7))

#pragma unroll
    for (int it = 0; it < 2; ++it) {
        int i = (t >> 3) + it * 32;
        int d = (t & 7) * 8;
        size_t row = (size_t)(1 + POS(i)) * 2304;
        bf16x8 qv = *reinterpret_cast<const bf16x8*>(&qkvb[row + 0    + h * 64 + d]);
        bf16x8 kv = *reinterpret_cast<const bf16x8*>(&qkvb[row + 768  + h * 64 + d]);
        us8    vv = *reinterpret_cast<const us8*>  (&qkvb[row + 1536 + h * 64 + d]);
        *reinterpret_cast<bf16x8*>(&qs[i * AST + d]) = qv;
        *reinterpret_cast<bf16x8*>(&ks[i * AST + d]) = kv;
#pragma unroll
        for (int e = 0; e < 8; ++e) vsT[(d + e) * AST + i] = vv[e];
    }
    if (t < 64) {
        size_t mi = ((size_t)b * HW_ + POS(t)) * C_;
        tok[t] = f ? m32[mi] : us2f(m16[mi]);
    }
    __syncthreads();

    const int wave = t >> 6;
    const int lane = t & 63;
    const int wm   = (wave >> 1) * 32;
    const int wn   = (wave & 1) * 32;
    const int frow = lane & 15;
    const int koff = (lane >> 4) * 8;
    const int crow = (lane >> 4) * 4;
    const int ccol = lane & 15;

    // ---- QK^T: S = Q @ K^T (wave tile 32x32, K=64) ----
    {
        f32x4 acc[2][2];
#pragma unroll
        for (int i = 0; i < 2; ++i)
#pragma unroll
            for (int j = 0; j < 2; ++j) acc[i][j] = (f32x4)0.0f;
#pragma unroll
        for (int kk = 0; kk < 64; kk += 32) {
            bf16x8 af[2], bfr[2];
#pragma unroll
            for (int i = 0; i < 2; ++i)
                af[i] = *reinterpret_cast<const bf16x8*>(&qs[(wm + i * 16 + frow) * AST + kk + koff]);
#pragma unroll
            for (int j = 0; j < 2; ++j)
                bfr[j] = *reinterpret_cast<const bf16x8*>(&ks[(wn + j * 16 + frow) * AST + kk + koff]);
#pragma unroll
            for (int i = 0; i < 2; ++i)
#pragma unroll
                for (int j = 0; j < 2; ++j)
                    acc[i][j] = __builtin_amdgcn_mfma_f32_16x16x32_bf16(af[i], bfr[j], acc[i][j], 0, 0, 0);
        }
#pragma unroll
        for (int i = 0; i < 2; ++i)
#pragma unroll
            for (int j = 0; j < 2; ++j)
#pragma unroll
                for (int r = 0; r < 4; ++r)
                    S[(wm + i * 16 + crow + r) * SST + wn + j * 16 + ccol] = acc[i][j][r];
    }
    __syncthreads();

    // ---- softmax: 4 lanes per row, 16 cols each ----
    {
        const int r = t >> 2;
        const int q = t & 3;
        const float tr = tok[r];
        float sv[16];
        float mx = -1e30f;
#pragma unroll
        for (int e = 0; e < 16; ++e) {
            int c = q * 16 + e;
            float s = S[r * SST + c] * 0.125f;
            if (tr * tok[c] == 0.0f) s = NEGV;
            sv[e] = s;
            mx = fmaxf(mx, s);
        }
        mx = fmaxf(mx, __shfl_xor(mx, 1));
        mx = fmaxf(mx, __shfl_xor(mx, 2));
        float sum = 0.f;
#pragma unroll
        for (int e = 0; e < 16; ++e) { sv[e] = __expf(sv[e] - mx); sum += sv[e]; }
        sum += __shfl_xor(sum, 1);
        sum += __shfl_xor(sum, 2);
        const float inv = 1.0f / sum;
        unsigned short* ps = qs;   // overlay (qs dead after QK^T)
        us8 o0, o1;
#pragma unroll
        for (int e = 0; e < 8; ++e) { o0[e] = f2us(sv[e] * inv); o1[e] = f2us(sv[8 + e] * inv); }
        *reinterpret_cast<us8*>(&ps[r * AST + q * 16])     = o0;
        *reinterpret_cast<us8*>(&ps[r * AST + q * 16 + 8]) = o1;
    }
    __syncthreads();

    // ---- PV: O = P @ V ----
    {
        const unsigned short* ps = qs;
        f32x4 acc[2][2];
#pragma unroll
        for (int i = 0; i < 2; ++i)
#pragma unroll
            for (int j = 0; j < 2; ++j) acc[i][j] = (f32x4)0.0f;
#pragma unroll
        for (int kk = 0; kk < 64; kk += 32) {
            bf16x8 af[2], bfr[2];
#pragma unroll
            for (int i = 0; i < 2; ++i)
                af[i] = *reinterpret_cast<const bf16x8*>(&ps[(wm + i * 16 + frow) * AST + kk + koff]);
#pragma unroll
            for (int j = 0; j < 2; ++j)
                bfr[j] = *reinterpret_cast<const bf16x8*>(&vsT[(wn + j * 16 + frow) * AST + kk + koff]);
#pragma unroll
            for (int i = 0; i < 2; ++i)
#pragma unroll
                for (int j = 0; j < 2; ++j)
                    acc[i][j] = __builtin_amdgcn_mfma_f32_16x16x32_bf16(af[i], bfr[j], acc[i][j], 0, 0, 0);
        }
#pragma unroll
        for (int i = 0; i < 2; ++i)
#pragma unroll
            for (int j = 0; j < 2; ++j)
#pragma unroll
                for (int r = 0; r < 4; ++r) {
                    int qrow = wm + i * 16 + crow + r;
                    int dcol = wn + j * 16 + ccol;
                    xcat[(size_t)(b * NTOK + 1 + POS(qrow)) * C_ + h * 64 + dcol] =
                        f2us(acc[i][j][r]);
                }
    }
#undef POS
}

// ---------------------------------------------------------------------------
// Cls attention, split-K partials (unchanged).
// ---------------------------------------------------------------------------
__global__ __launch_bounds__(256) void cls_part(
    const unsigned short* __restrict__ qkv2,
    const unsigned short* __restrict__ m16, const float* __restrict__ m32,
    const unsigned short* __restrict__ g16, const float* __restrict__ g32,
    const int* __restrict__ flagp,
    float* __restrict__ part,      // [B][NH][NSPLIT][68]
    int b0)
{
    __shared__ float q[64];
    __shared__ float e[256];
    __shared__ float red[256];
    __shared__ float osum[4][64];
    __shared__ float Mv, Sv;

    const int h  = blockIdx.x;
    const int sp = blockIdx.y;
    const int bb = blockIdx.z;
    const int b  = b0 + bb;
    const int t  = threadIdx.x;
    const int f  = *flagp;
    const unsigned short* qkvb = qkv2 + (size_t)bb * NTOK * 2304;

    if (t < 64) q[t] = us2f(qkvb[h * 64 + t]);   // row 0 = cls token
    __syncthreads();

    const int j = sp * 256 + t;                   // key 0..4095
    const unsigned short* krow = &qkvb[(size_t)(1 + j) * 2304 + 768 + h * 64];
    float s = 0.f;
#pragma unroll
    for (int dd = 0; dd < 8; ++dd) {
        us8 kv8 = *reinterpret_cast<const us8*>(&krow[dd * 8]);
#pragma unroll
        for (int ee = 0; ee < 8; ++ee) s += q[dd * 8 + ee] * us2f(kv8[ee]);
    }
    s *= 0.125f;
    {
        size_t mi = ((size_t)b * HW_ + j) * C_;
        size_t gi = ((size_t)b * NH_ + h) * HW_ + j;
        float tokj = f ? m32[mi] : us2f(m16[mi]);
        float gmj  = f ? g32[gi] : us2f(g16[gi]);
        if (tokj * gmj == 0.0f) s = NEGV;
    }

    red[t] = s; __syncthreads();
    for (int k2 = 128; k2 > 0; k2 >>= 1) { if (t < k2) red[t] = fmaxf(red[t], red[t + k2]); __syncthreads(); }
    const float m = red[0]; __syncthreads();

    float ev = __expf(s - m);
    e[t] = ev; red[t] = ev; __syncthreads();
    for (int k2 = 128; k2 > 0; k2 >>= 1) { if (t < k2) red[t] += red[t + k2]; __syncthreads(); }
    if (t == 0) { Mv = m; Sv = red[0]; }

    const int wv = t >> 6, l = t & 63;
    float accv = 0.f;
    const unsigned short* vbase =
        &qkvb[(size_t)(1 + sp * 256 + wv * 64) * 2304 + 1536 + h * 64 + l];
    for (int kk = 0; kk < 64; ++kk)
        accv += e[wv * 64 + kk] * us2f(vbase[(size_t)kk * 2304]);
    osum[wv][l] = accv;
    __syncthreads();

    const size_t pi = ((size_t)(b * NH_ + h) * NSPLIT + sp) * 68;
    if (t < 64)
        part[pi + t] = osum[0][t] + osum[1][t] + osum[2][t] + osum[3][t];
    if (t == 64 + 0) part[pi + 64] = Mv;
    if (t == 64 + 1) part[pi + 65] = Sv;
}

// ---------------------------------------------------------------------------
// Combine split partials (log-sum-exp merge) -> xcat cls rows (bf16)
// ---------------------------------------------------------------------------
__global__ __launch_bounds__(64) void cls_reduce(
    const float* __restrict__ part, unsigned short* __restrict__ xcat)
{
    const int h = blockIdx.x, b = blockIdx.y, t = threadIdx.x;
    const float* pb = &part[((size_t)(b * NH_ + h) * NSPLIT) * 68];
    float gm = -1e30f;
    for (int i = 0; i < NSPLIT; ++i) gm = fmaxf(gm, pb[i * 68 + 64]);
    float S = 0.f, acc = 0.f;
    for (int i = 0; i < NSPLIT; ++i) {
        float w = __expf(pb[i * 68 + 64] - gm);
        S   += pb[i * 68 + 65] * w;
        acc += pb[i * 68 + t]  * w;
    }
    xcat[(size_t)(b * NTOK) * C_ + h * 64 + t] = f2us(acc / S);
}

// ---------------------------------------------------------------------------
// v_cls GEMV + broadcast-add (unchanged).
// ---------------------------------------------------------------------------
__global__ __launch_bounds__(256) void add_vcls(
    const unsigned short* __restrict__ xcat, unsigned short* __restrict__ xcatc,
    const unsigned short* __restrict__ kv16, const float* __restrict__ kv32,
    const int* __restrict__ flagp)
{
    __shared__ float xr[768];
    __shared__ float psum[4][64];
    __shared__ float vc[64];

    const int blk = blockIdx.x;
    const int rsp = blockIdx.y;
    const int b   = blk / 12;
    const int c0  = (blk % 12) * 64;
    const int t   = threadIdx.x;
    const int f   = *flagp;

    for (int it = 0; it < 3; ++it) {
        int k = t + it * 256;
        xr[k] = us2f(xcat[(size_t)(b * NTOK) * C_ + k]);
    }
    __syncthreads();

    const int cc = t & 63, kq = t >> 6;
    float p = 0.f;
    for (int k = kq * 192; k < kq * 192 + 192; ++k) {
        size_t wi = (size_t)k * 1536 + 768 + c0 + cc;
        p += xr[k] * (f ? kv32[wi] : us2f(kv16[wi]));
    }
    psum[kq][cc] = p;
    __syncthreads();
    if (t < 64) vc[t] = psum[0][t] + psum[1][t] + psum[2][t] + psum[3][t];
    __syncthreads();

    const int ch8  = (t & 7) * 8;
    const int rsub = t >> 3;
    for (int it = 0; it < 32; ++it) {
        int row = rsp * 1024 + it * 32 + rsub;
        size_t off = (size_t)(b * NTOK + 1 + row) * C_ + c0 + ch8;
        us8 vv = *reinterpret_cast<const us8*>(&xcat[off]);
#pragma unroll
        for (int e2 = 0; e2 < 8; ++e2)
            vv[e2] = f2us(us2f(vv[e2]) + vc[ch8 + e2]);
        *reinterpret_cast<us8*>(&xcatc[off]) = vv;
    }
    if (rsp == 0 && t < 64)
        xcatc[(size_t)(b * NTOK) * C_ + c0 + t] = xcat[(size_t)(b * NTOK) * C_ + c0 + t];
}

// ---------------------------------------------------------------------------
// Workspace plans.
// Small-ws (proven safe, ws >= 51,523,712):
//   [0,128) flag | [128, 37,758,080) qkv_2b | [37,758,080, 41,297,024) qkv_wT
//   [41,297,024, 41,714,816) part | [128, 50,344,064) xcatc (after above die)
//   [50,344,064, 51,523,712) pwT
// Big-ws fused (ws >= 156,168,320):
//   [0,128) flag | [128, 151,031,936) qkv_full (all 8 batches)
//   [151,031,936, 154,570,880) qkv_wT | [154,570,880, 154,988,672) part
//   [154,988,672, 156,168,320) pwT | xcatc overlays [128, ...) after qkv dead
// ---------------------------------------------------------------------------
extern "C" void kernel_launch(void* const* d_in, const int* in_sizes, int n_in,
                              void* d_out, int out_size, void* d_ws, size_t ws_size,
                              hipStream_t stream)
{
    const unsigned short* x16  = (const unsigned short*)d_in[0];
    const float*          x32  = (const float*)d_in[0];
    const unsigned short* m16  = (const unsigned short*)d_in[1];
    const float*          m32  = (const float*)d_in[1];
    const unsigned short* g16  = (const unsigned short*)d_in[2];
    const float*          g32  = (const float*)d_in[2];
    const unsigned short* qw16 = (const unsigned short*)d_in[3];
    const float*          qw32 = (const float*)d_in[3];
    const unsigned short* kv16 = (const unsigned short*)d_in[4];
    const float*          kv32 = (const float*)d_in[4];
    const unsigned short* pw16 = (const unsigned short*)d_in[5];
    const float*          pw32 = (const float*)d_in[5];
    const unsigned short* pb16 = (const unsigned short*)d_in[6];
    const float*          pb32 = (const float*)d_in[6];

    char* ws = (char*)d_ws;
    int*            flag  = (int*)ws;
    unsigned short* xcatc = (unsigned short*)(ws + 128);
    unsigned short* xcat  = (unsigned short*)d_out;

    const bool fused = (ws_size >= (size_t)156168320);

    detect_dtype<<<1, 256, 0, stream>>>((const unsigned int*)d_in[0], flag);

    if (fused) {
        unsigned short* qkv_full = (unsigned short*)(ws + 128);
        unsigned short* qkv_wT   = (unsigned short*)(ws + 151031936);
        float*          part     = (float*)(ws + 154570880);
        unsigned short* pwT      = (unsigned short*)(ws + 154988672);

        transpose_w<<<(2304 * 768 + 255) / 256, 256, 0, stream>>>(
            qw16, qw32, flag, qkv_wT, 768, 2304);
        transpose_w<<<(768 * 768 + 255) / 256, 256, 0, stream>>>(
            pw16, pw32, flag, pwT, 768, 768);

        gemm_bt<<<dim3(18, 257), 256, 0, stream>>>(
            x16, x32, flag, qkv_wT,
            nullptr, nullptr, nullptr,
            qkv_full, nullptr,
            MTOT, 2304, 768, 0);
        win_attn<<<dim3(64, 12, 8), 256, 0, stream>>>(qkv_full, m16, m32, flag, xcat, 0);
        cls_part<<<dim3(12, NSPLIT, 8), 256, 0, stream>>>(
            qkv_full, m16, m32, g16, g32, flag, part, 0);

        cls_reduce<<<dim3(12, 8), 64, 0, stream>>>(part, xcat);
        add_vcls<<<dim3(96, 4), 256, 0, stream>>>(xcat, xcatc, kv16, kv32, flag);

        gemm_bt<<<dim3(6, 257), 256, 0, stream>>>(
            xcatc, nullptr, nullptr, pwT,
            pb16, pb32, flag,
            d_out, flag,
            MTOT, 768, 768, 0);
        return;
    }

    unsigned short* qkv_2b = (unsigned short*)(ws + 128);
    unsigned short* qkv_wT = (unsigned short*)(ws + 37758080);
    float*          part   = (float*)(ws + 41297024);
    unsigned short* pwT    = (unsigned short*)(ws + 50344064);
    const bool fastproj = (ws_size >= (size_t)51523712);

    transpose_w<<<(2304 * 768 + 255) / 256, 256, 0, stream>>>(
        qw16, qw32, flag, qkv_wT, 768, 2304);
    if (fastproj)
        transpose_w<<<(768 * 768 + 255) / 256, 256, 0, stream>>>(
            pw16, pw32, flag, pwT, 768, 768);

    for (int b0 = 0; b0 < B_; b0 += 2) {
        gemm_bt<<<dim3(18, 65), 256, 0, stream>>>(
            x16, x32, flag, qkv_wT,
            nullptr, nullptr, nullptr,
            qkv_2b, nullptr,
            2 * NTOK, 2304, 768, (long)b0 * NTOK);
        win_attn<<<dim3(64, 12, 2), 256, 0, stream>>>(qkv_2b, m16, m32, flag, xcat, b0);
        cls_part<<<dim3(12, NSPLIT, 2), 256, 0, stream>>>(
            qkv_2b, m16, m32, g16, g32, flag, part, b0);
    }

    cls_reduce<<<dim3(12, 8), 64, 0, stream>>>(part, xcat);
    add_vcls<<<dim3(96, 4), 256, 0, stream>>>(xcat, xcatc, kv16, kv32, flag);

    if (fastproj) {
        gemm_bt<<<dim3(6, 257), 256, 0, stream>>>(
            xcatc, nullptr, nullptr, pwT,
            pb16, pb32, flag,
            d_out, flag,
            MTOT, 768, 768, 0);
    } else {
        gemm_univ<<<dim3(6, 257), 256, 0, stream>>>(
            xcatc, nullptr, nullptr, pw16, pw32, flag, 1,
            pb16, pb32, d_out, flag,
            MTOT, 768, 768, 0);
    }
}

// Round 7
// 664.567 us; speedup vs baseline: 1.2191x; 1.1243x over previous
//
#include <hip/hip_runtime.h>

// Problem constants: B=8, C=768, NH=12, WS=8, NC=1, H=W=64
#define B_    8
#define C_    768
#define NH_   12
#define HW_   4096
#define NTOK  4097
#define MTOT  32776         // B_ * NTOK
#define NEGV  (-10000.0f)
#define NSPLIT 16

typedef __bf16 bf16x8 __attribute__((ext_vector_type(8)));
typedef float  f32x4  __attribute__((ext_vector_type(4)));
typedef unsigned short us8 __attribute__((ext_vector_type(8)));

// addrspace casts for global_load_lds
#define GLB(p) ((const __attribute__((address_space(1))) void*)(p))
#define LDS(p) ((__attribute__((address_space(3))) void*)(p))

__device__ __forceinline__ float us2f(unsigned short u) {
    unsigned int v = ((unsigned int)u) << 16;
    float f; __builtin_memcpy(&f, &v, 4);
    return f;
}
__device__ __forceinline__ unsigned short f2us(float f) {
    unsigned int v; __builtin_memcpy(&v, &f, 4);
    v += 0x7FFFu + ((v >> 16) & 1u);   // RNE
    return (unsigned short)(v >> 16);
}

// ---------------------------------------------------------------------------
// Runtime dtype detect (flag=1 -> fp32 inputs).
// ---------------------------------------------------------------------------
__global__ __launch_bounds__(256) void detect_dtype(
    const unsigned int* __restrict__ xw, int* __restrict__ flag)
{
    __shared__ int s[256];
    int t = threadIdx.x, cnt = 0;
    for (int i = t; i < 4096; i += 256) {
        unsigned e = (xw[i] >> 23) & 0xFFu;
        cnt += (e >= 64u && e <= 191u) ? 1 : 0;
    }
    s[t] = cnt; __syncthreads();
    for (int k = 128; k > 0; k >>= 1) { if (t < k) s[t] += s[t + k]; __syncthreads(); }
    if (t == 0) *flag = (s[0] > 2048) ? 1 : 0;
}

// ---------------------------------------------------------------------------
// Generic weight transpose: src (Kd x Nd, flag dtype) -> dst (Nd x Kd, bf16)
// ---------------------------------------------------------------------------
__global__ __launch_bounds__(256) void transpose_w(
    const unsigned short* __restrict__ s16, const float* __restrict__ s32,
    const int* __restrict__ flagp, unsigned short* __restrict__ dst,
    int Kd, int Nd)
{
    int o = blockIdx.x * 256 + threadIdx.x;
    if (o >= Kd * Nd) return;
    int n = o / Kd, k = o % Kd;
    dst[o] = (*flagp) ? f2us(s32[(size_t)k * Nd + n]) : s16[(size_t)k * Nd + n];
}

// ---------------------------------------------------------------------------
// Fast GEMM: 128x128 tile, BK=64, 4 waves, 16x16x32 MFMA, single-buffered.
// r4: LDS XOR swizzle (bank conflicts = 0). r5: XCD-aware bijective chunked
// blockIdx swizzle (FETCH 464->187 MB). r6 dbuf reverted (null; m114: the
// latency cover on this structure is CO-RESIDENT BLOCKS, not intra-block
// pipelining).
// r7: register diet for 3 blocks/CU: single SGPR base + 32-bit voffsets
// (saddr-form loads) replace 12 64-bit pointers; fp32-path pointers moved
// into the cold branch; __launch_bounds__(256,3) pins 3 waves/SIMD.
// ---------------------------------------------------------------------------
__global__ __launch_bounds__(256, 3) void gemm_bt(
    const unsigned short* __restrict__ A16, const float* __restrict__ A32,
    const int* __restrict__ aflagp,
    const unsigned short* __restrict__ BT,
    const unsigned short* __restrict__ bias16, const float* __restrict__ bias32,
    const int* __restrict__ bflagp,
    void* __restrict__ Cout, const int* __restrict__ oflagp,
    int M, int Nd, int K, long arow0)
{
    __shared__ __align__(16) unsigned short As[128 * 64];   // 16 KB
    __shared__ __align__(16) unsigned short Bs[128 * 64];   // 16 KB

    const int fa = aflagp ? *aflagp : 0;
    const int fb = bflagp ? *bflagp : 0;
    const int fo = oflagp ? *oflagp : 0;

    const int t = threadIdx.x;

    // ---- XCD-aware bijective chunked swizzle (m204) ----
    const int nbx = gridDim.x;
    const int nwg = nbx * gridDim.y;
    const int lin = blockIdx.y * nbx + blockIdx.x;
    const int q   = nwg >> 3, r = nwg & 7;
    const int xcd = lin & 7, loc = lin >> 3;
    const int wg  = (xcd < r ? xcd * (q + 1) : r * (q + 1) + (xcd - r) * q) + loc;
    const int m0  = (wg / nbx) * 128;
    const int n0  = (wg % nbx) * 128;

    const int wave = t >> 6;
    const int lane = t & 63;
    const int wm   = (wave >> 1) * 64;
    const int wn   = (wave & 1) * 64;
    const int frow = lane & 15;
    const int lsl  = lane >> 4;          // k-slot base within 32-wide half

    f32x4 acc[4][4];
#pragma unroll
    for (int i = 0; i < 4; ++i)
#pragma unroll
        for (int j = 0; j < 4; ++j) acc[i][j] = (f32x4)0.0f;

    // staging geometry (per 128x64 tile): thread t, chunk it in 0..3:
    //   dest row r = (t>>3) + it*32, dest elem = it*2048 + t*8 (linear 16B)
    //   source col = ((t&7) ^ (r&7))*8   (inverse swizzle; read side XORs back)
    const int tr   = t >> 3;
    const int srcc = (((t & 7) ^ (tr & 7)) * 8);

    // 32-bit element offsets (saddr-form addressing; max 32775*768+768 < 2^25)
    unsigned oA[4], oB[4];
#pragma unroll
    for (int it = 0; it < 4; ++it) {
        int ga = m0 + tr + it * 32; if (ga >= M)  ga = M - 1;
        int gb = n0 + tr + it * 32; if (gb >= Nd) gb = Nd - 1;
        oA[it] = (unsigned)ga * (unsigned)K + (unsigned)srcc;
        oB[it] = (unsigned)gb * (unsigned)K + (unsigned)srcc;
    }
    const unsigned short* aBase = A16 + (size_t)arow0 * K;

    if (!fa) {
        for (int k0 = 0; k0 < K; k0 += 64) {
#pragma unroll
            for (int it = 0; it < 4; ++it) {
                __builtin_amdgcn_global_load_lds(GLB(aBase + oA[it] + k0),
                    LDS(&As[it * 2048 + t * 8]), 16, 0, 0);
                __builtin_amdgcn_global_load_lds(GLB(BT + oB[it] + k0),
                    LDS(&Bs[it * 2048 + t * 8]), 16, 0, 0);
            }
            __syncthreads();

#pragma unroll
            for (int kk = 0; kk < 64; kk += 32) {
                const int ksl = (kk >> 3) + lsl;   // global k-slot 0..7
                bf16x8 af[4], bfr[4];
#pragma unroll
                for (int i = 0; i < 4; ++i) {
                    int ra = wm + i * 16 + frow;
                    af[i] = *reinterpret_cast<const bf16x8*>(&As[ra * 64 + ((ksl ^ (ra & 7)) << 3)]);
                }
#pragma unroll
                for (int j = 0; j < 4; ++j) {
                    int rb = wn + j * 16 + frow;
                    bfr[j] = *reinterpret_cast<const bf16x8*>(&Bs[rb * 64 + ((ksl ^ (rb & 7)) << 3)]);
                }
#pragma unroll
                for (int i = 0; i < 4; ++i)
#pragma unroll
                    for (int j = 0; j < 4; ++j)
                        acc[i][j] = __builtin_amdgcn_mfma_f32_16x16x32_bf16(af[i], bfr[j], acc[i][j], 0, 0, 0);
            }
            __syncthreads();
        }
    } else {
        // ---- fp32 A fallback (cold; pointers computed in-branch) ----
        const float* aBase32 = A32 + (size_t)arow0 * K;
        for (int k0 = 0; k0 < K; k0 += 64) {
#pragma unroll
            for (int it = 0; it < 4; ++it) {
                unsigned short tmp[8];
                const float* p = aBase32 + oA[it] + k0;
#pragma unroll
                for (int e = 0; e < 8; ++e) tmp[e] = f2us(p[e]);
                *reinterpret_cast<us8*>(&As[it * 2048 + t * 8]) = *reinterpret_cast<us8*>(tmp);
                __builtin_amdgcn_global_load_lds(GLB(BT + oB[it] + k0),
                    LDS(&Bs[it * 2048 + t * 8]), 16, 0, 0);
            }
            __syncthreads();

#pragma unroll
            for (int kk = 0; kk < 64; kk += 32) {
                const int ksl = (kk >> 3) + lsl;
                bf16x8 af[4], bfr[4];
#pragma unroll
                for (int i = 0; i < 4; ++i) {
                    int ra = wm + i * 16 + frow;
                    af[i] = *reinterpret_cast<const bf16x8*>(&As[ra * 64 + ((ksl ^ (ra & 7)) << 3)]);
                }
#pragma unroll
                for (int j = 0; j < 4; ++j) {
                    int rb = wn + j * 16 + frow;
                    bfr[j] = *reinterpret_cast<const bf16x8*>(&Bs[rb * 64 + ((ksl ^ (rb & 7)) << 3)]);
                }
#pragma unroll
                for (int i = 0; i < 4; ++i)
#pragma unroll
                    for (int j = 0; j < 4; ++j)
                        acc[i][j] = __builtin_amdgcn_mfma_f32_16x16x32_bf16(af[i], bfr[j], acc[i][j], 0, 0, 0);
            }
            __syncthreads();
        }
    }

    const int crow = (lane >> 4) * 4;
    const int ccol = lane & 15;
    unsigned short* C16 = (unsigned short*)Cout;
    float*          C32 = (float*)Cout;
#pragma unroll
    for (int i = 0; i < 4; ++i)
#pragma unroll
        for (int j = 0; j < 4; ++j) {
            int gn = n0 + wn + j * 16 + ccol;
            float bv = 0.0f;
            if (bias16) bv = fb ? bias32[gn] : us2f(bias16[gn]);
#pragma unroll
            for (int r2 = 0; r2 < 4; ++r2) {
                int gm = m0 + wm + i * 16 + crow + r2;
                if (gm < M) {
                    float v = acc[i][j][r2] + bv;
                    if (fo) C32[(size_t)gm * Nd + gn] = v;
                    else    C16[(size_t)gm * Nd + gn] = f2us(v);
                }
            }
        }
}

// ---------------------------------------------------------------------------
// Universal GEMM (fallback for proj when ws too small for pwT).
// ---------------------------------------------------------------------------
#define LSTR 40   // 32+8 pad; 80 B rows, 16B-aligned

__global__ __launch_bounds__(256) void gemm_univ(
    const unsigned short* __restrict__ A16, const float* __restrict__ A32,
    const int* __restrict__ aflagp,
    const unsigned short* __restrict__ B16, const float* __restrict__ B32,
    const int* __restrict__ bflagp, int btmode,
    const unsigned short* __restrict__ bias16, const float* __restrict__ bias32,
    void* __restrict__ Cout, const int* __restrict__ oflagp,
    int M, int Nd, int K, long arow0)
{
    __shared__ __align__(16) unsigned short As[128 * LSTR];
    __shared__ __align__(16) unsigned short Bs[128 * LSTR];

    const int fa = aflagp ? *aflagp : 0;
    const int fb = bflagp ? *bflagp : 0;
    const int fo = oflagp ? *oflagp : 0;

    const int t    = threadIdx.x;
    const int m0   = blockIdx.y * 128;
    const int n0   = blockIdx.x * 128;
    const int wave = t >> 6;
    const int lane = t & 63;
    const int wm   = (wave >> 1) * 64;
    const int wn   = (wave & 1) * 64;
    const int frow = lane & 15;
    const int koff = (lane >> 4) * 8;

    f32x4 acc[4][4];
#pragma unroll
    for (int i = 0; i < 4; ++i)
#pragma unroll
        for (int j = 0; j < 4; ++j) acc[i][j] = (f32x4)0.0f;

    const int sr = t >> 2;
    const int sc = (t & 3) * 8;

    for (int k0 = 0; k0 < K; k0 += 32) {
#pragma unroll
        for (int it = 0; it < 2; ++it) {
            int r = sr + it * 64;
            int gl = m0 + r; if (gl >= M) gl = M - 1;
            size_t grow = (size_t)(arow0 + gl);
            if (fa) {
                const float* p = &A32[grow * K + k0 + sc];
                unsigned short tmp[8];
#pragma unroll
                for (int e = 0; e < 8; ++e) tmp[e] = f2us(p[e]);
                *reinterpret_cast<us8*>(&As[r * LSTR + sc]) = *reinterpret_cast<us8*>(tmp);
            } else {
                *reinterpret_cast<bf16x8*>(&As[r * LSTR + sc]) =
                    *reinterpret_cast<const bf16x8*>(&A16[grow * K + k0 + sc]);
            }
        }
        if (btmode == 0) {
#pragma unroll
            for (int it = 0; it < 2; ++it) {
                int r = sr + it * 64;
                int gn = n0 + r; if (gn >= Nd) gn = Nd - 1;
                *reinterpret_cast<bf16x8*>(&Bs[r * LSTR + sc]) =
                    *reinterpret_cast<const bf16x8*>(&B16[(size_t)gn * K + k0 + sc]);
            }
        } else {
            const int kr = t >> 3;
            const int nc = (t & 7) * 16;
            if (fb) {
                const float* p = &B32[(size_t)(k0 + kr) * Nd + n0 + nc];
#pragma unroll
                for (int e = 0; e < 16; ++e) Bs[(nc + e) * LSTR + kr] = f2us(p[e]);
            } else {
                const unsigned short* p = &B16[(size_t)(k0 + kr) * Nd + n0 + nc];
#pragma unroll
                for (int e = 0; e < 16; ++e) Bs[(nc + e) * LSTR + kr] = p[e];
            }
        }
        __syncthreads();

        bf16x8 af[4], bfr[4];
#pragma unroll
        for (int i = 0; i < 4; ++i)
            af[i] = *reinterpret_cast<const bf16x8*>(&As[(wm + i * 16 + frow) * LSTR + koff]);
#pragma unroll
        for (int j = 0; j < 4; ++j)
            bfr[j] = *reinterpret_cast<const bf16x8*>(&Bs[(wn + j * 16 + frow) * LSTR + koff]);
#pragma unroll
        for (int i = 0; i < 4; ++i)
#pragma unroll
            for (int j = 0; j < 4; ++j)
                acc[i][j] = __builtin_amdgcn_mfma_f32_16x16x32_bf16(af[i], bfr[j], acc[i][j], 0, 0, 0);
        __syncthreads();
    }

    const int crow = (lane >> 4) * 4;
    const int ccol = lane & 15;
    unsigned short* C16 = (unsigned short*)Cout;
    float*          C32 = (float*)Cout;
#pragma unroll
    for (int i = 0; i < 4; ++i)
#pragma unroll
        for (int j = 0; j < 4; ++j) {
            int gn = n0 + wn + j * 16 + ccol;
            float bv = 0.0f;
            if (bias16) bv = fb ? bias32[gn] : us2f(bias16[gn]);
#pragma unroll
            for (int r = 0; r < 4; ++r) {
                int gm = m0 + wm + i * 16 + crow + r;
                if (gm < M) {
                    float v = acc[i][j][r] + bv;
                    if (fo) C32[(size_t)gm * Nd + gn] = v;
                    else    C16[(size_t)gm * Nd + gn] = f2us(v);
                }
            }
        }
}

// ---------------------------------------------------------------------------
// Window attention, MFMA version. Block = (window, head, bb), 4 waves.
// ---------------------------------------------------------------------------
#define AST 72    // bf16 tile stride (elements)
#define SST 65    // S f32 stride (elements)

__global__ __launch_bounds__(256) void win_attn(
    const unsigned short* __restrict__ qkv2,
    const unsigned short* __restrict__ m16, const float* __restrict__ m32,
    const int* __restrict__ flagp,
    unsigned short* __restrict__ xcat, int b0)
{
    __shared__ __align__(16) unsigned short qs[64 * AST];   // reused as ps
    __shared__ __align__(16) unsigned short ks[64 * AST];
    __shared__ __align__(16) unsigned short vsT[64 * AST];  // [d][key]
    __shared__ float S[64 * SST];
    __shared__ float tok[64];

    const int w  = blockIdx.x;
    const int h  = blockIdx.y;
    const int bb = blockIdx.z;
    const int b  = b0 + bb;
    const int hb = w >> 3, wb = w & 7;
    const int t  = threadIdx.x;
    const int f  = *flagp;
    const unsigned short* qkvb = qkv2 + (size_t)bb * NTOK * 2304;

#define POS(i) ((hb * 8 + ((i) >> 3)) * 64 + wb * 8 + ((i) & 7))

#pragma unroll
    for (int it = 0; it < 2; ++it) {
        int i = (t >> 3) + it * 32;
        int d = (t & 7) * 8;
        size_t row = (size_t)(1 + POS(i)) * 2304;
        bf16x8 qv = *reinterpret_cast<const bf16x8*>(&qkvb[row + 0    + h * 64 + d]);
        bf16x8 kv = *reinterpret_cast<const bf16x8*>(&qkvb[row + 768  + h * 64 + d]);
        us8    vv = *reinterpret_cast<const us8*>  (&qkvb[row + 1536 + h * 64 + d]);
        *reinterpret_cast<bf16x8*>(&qs[i * AST + d]) = qv;
        *reinterpret_cast<bf16x8*>(&ks[i * AST + d]) = kv;
#pragma unroll
        for (int e = 0; e < 8; ++e) vsT[(d + e) * AST + i] = vv[e];
    }
    if (t < 64) {
        size_t mi = ((size_t)b * HW_ + POS(t)) * C_;
        tok[t] = f ? m32[mi] : us2f(m16[mi]);
    }
    __syncthreads();

    const int wave = t >> 6;
    const int lane = t & 63;
    const int wm   = (wave >> 1) * 32;
    const int wn   = (wave & 1) * 32;
    const int frow = lane & 15;
    const int koff = (lane >> 4) * 8;
    const int crow = (lane >> 4) * 4;
    const int ccol = lane & 15;

    // ---- QK^T: S = Q @ K^T (wave tile 32x32, K=64) ----
    {
        f32x4 acc[2][2];
#pragma unroll
        for (int i = 0; i < 2; ++i)
#pragma unroll
            for (int j = 0; j < 2; ++j) acc[i][j] = (f32x4)0.0f;
#pragma unroll
        for (int kk = 0; kk < 64; kk += 32) {
            bf16x8 af[2], bfr[2];
#pragma unroll
            for (int i = 0; i < 2; ++i)
                af[i] = *reinterpret_cast<const bf16x8*>(&qs[(wm + i * 16 + frow) * AST + kk + koff]);
#pragma unroll
            for (int j = 0; j < 2; ++j)
                bfr[j] = *reinterpret_cast<const bf16x8*>(&ks[(wn + j * 16 + frow) * AST + kk + koff]);
#pragma unroll
            for (int i = 0; i < 2; ++i)
#pragma unroll
                for (int j = 0; j < 2; ++j)
                    acc[i][j] = __builtin_amdgcn_mfma_f32_16x16x32_bf16(af[i], bfr[j], acc[i][j], 0, 0, 0);
        }
#pragma unroll
        for (int i = 0; i < 2; ++i)
#pragma unroll
            for (int j = 0; j < 2; ++j)
#pragma unroll
                for (int r = 0; r < 4; ++r)
                    S[(wm + i * 16 + crow + r) * SST + wn + j * 16 + ccol] = acc[i][j][r];
    }
    __syncthreads();

    // ---- softmax: 4 lanes per row, 16 cols each ----
    {
        const int r = t >> 2;
        const int q = t & 3;
        const float tr = tok[r];
        float sv[16];
        float mx = -1e30f;
#pragma unroll
        for (int e = 0; e < 16; ++e) {
            int c = q * 16 + e;
            float s = S[r * SST + c] * 0.125f;
            if (tr * tok[c] == 0.0f) s = NEGV;
            sv[e] = s;
            mx = fmaxf(mx, s);
        }
        mx = fmaxf(mx, __shfl_xor(mx, 1));
        mx = fmaxf(mx, __shfl_xor(mx, 2));
        float sum = 0.f;
#pragma unroll
        for (int e = 0; e < 16; ++e) { sv[e] = __expf(sv[e] - mx); sum += sv[e]; }
        sum += __shfl_xor(sum, 1);
        sum += __shfl_xor(sum, 2);
        const float inv = 1.0f / sum;
        unsigned short* ps = qs;   // overlay (qs dead after QK^T)
        us8 o0, o1;
#pragma unroll
        for (int e = 0; e < 8; ++e) { o0[e] = f2us(sv[e] * inv); o1[e] = f2us(sv[8 + e] * inv); }
        *reinterpret_cast<us8*>(&ps[r * AST + q * 16])     = o0;
        *reinterpret_cast<us8*>(&ps[r * AST + q * 16 + 8]) = o1;
    }
    __syncthreads();

    // ---- PV: O = P @ V ----
    {
        const unsigned short* ps = qs;
        f32x4 acc[2][2];
#pragma unroll
        for (int i = 0; i < 2; ++i)
#pragma unroll
            for (int j = 0; j < 2; ++j) acc[i][j] = (f32x4)0.0f;
#pragma unroll
        for (int kk = 0; kk < 64; kk += 32) {
            bf16x8 af[2], bfr[2];
#pragma unroll
            for (int i = 0; i < 2; ++i)
                af[i] = *reinterpret_cast<const bf16x8*>(&ps[(wm + i * 16 + frow) * AST + kk + koff]);
#pragma unroll
            for (int j = 0; j < 2; ++j)
                bfr[j] = *reinterpret_cast<const bf16x8*>(&vsT[(wn + j * 16 + frow) * AST + kk + koff]);
#pragma unroll
            for (int i = 0; i < 2; ++i)
#pragma unroll
                for (int j = 0; j < 2; ++j)
                    acc[i][j] = __builtin_amdgcn_mfma_f32_16x16x32_bf16(af[i], bfr[j], acc[i][j], 0, 0, 0);
        }
#pragma unroll
        for (int i = 0; i < 2; ++i)
#pragma unroll
            for (int j = 0; j < 2; ++j)
#pragma unroll
                for (int r = 0; r < 4; ++r) {
                    int qrow = wm + i * 16 + crow + r;
                    int dcol = wn + j * 16 + ccol;
                    xcat[(size_t)(b * NTOK + 1 + POS(qrow)) * C_ + h * 64 + dcol] =
                        f2us(acc[i][j][r]);
                }
    }
#undef POS
}

// ---------------------------------------------------------------------------
// Cls attention, split-K partials (unchanged).
// ---------------------------------------------------------------------------
__global__ __launch_bounds__(256) void cls_part(
    const unsigned short* __restrict__ qkv2,
    const unsigned short* __restrict__ m16, const float* __restrict__ m32,
    const unsigned short* __restrict__ g16, const float* __restrict__ g32,
    const int* __restrict__ flagp,
    float* __restrict__ part,      // [B][NH][NSPLIT][68]
    int b0)
{
    __shared__ float q[64];
    __shared__ float e[256];
    __shared__ float red[256];
    __shared__ float osum[4][64];
    __shared__ float Mv, Sv;

    const int h  = blockIdx.x;
    const int sp = blockIdx.y;
    const int bb = blockIdx.z;
    const int b  = b0 + bb;
    const int t  = threadIdx.x;
    const int f  = *flagp;
    const unsigned short* qkvb = qkv2 + (size_t)bb * NTOK * 2304;

    if (t < 64) q[t] = us2f(qkvb[h * 64 + t]);   // row 0 = cls token
    __syncthreads();

    const int j = sp * 256 + t;                   // key 0..4095
    const unsigned short* krow = &qkvb[(size_t)(1 + j) * 2304 + 768 + h * 64];
    float s = 0.f;
#pragma unroll
    for (int dd = 0; dd < 8; ++dd) {
        us8 kv8 = *reinterpret_cast<const us8*>(&krow[dd * 8]);
#pragma unroll
        for (int ee = 0; ee < 8; ++ee) s += q[dd * 8 + ee] * us2f(kv8[ee]);
    }
    s *= 0.125f;
    {
        size_t mi = ((size_t)b * HW_ + j) * C_;
        size_t gi = ((size_t)b * NH_ + h) * HW_ + j;
        float tokj = f ? m32[mi] : us2f(m16[mi]);
        float gmj  = f ? g32[gi] : us2f(g16[gi]);
        if (tokj * gmj == 0.0f) s = NEGV;
    }

    red[t] = s; __syncthreads();
    for (int k2 = 128; k2 > 0; k2 >>= 1) { if (t < k2) red[t] = fmaxf(red[t], red[t + k2]); __syncthreads(); }
    const float m = red[0]; __syncthreads();

    float ev = __expf(s - m);
    e[t] = ev; red[t] = ev; __syncthreads();
    for (int k2 = 128; k2 > 0; k2 >>= 1) { if (t < k2) red[t] += red[t + k2]; __syncthreads(); }
    if (t == 0) { Mv = m; Sv = red[0]; }

    const int wv = t >> 6, l = t & 63;
    float accv = 0.f;
    const unsigned short* vbase =
        &qkvb[(size_t)(1 + sp * 256 + wv * 64) * 2304 + 1536 + h * 64 + l];
    for (int kk = 0; kk < 64; ++kk)
        accv += e[wv * 64 + kk] * us2f(vbase[(size_t)kk * 2304]);
    osum[wv][l] = accv;
    __syncthreads();

    const size_t pi = ((size_t)(b * NH_ + h) * NSPLIT + sp) * 68;
    if (t < 64)
        part[pi + t] = osum[0][t] + osum[1][t] + osum[2][t] + osum[3][t];
    if (t == 64 + 0) part[pi + 64] = Mv;
    if (t == 64 + 1) part[pi + 65] = Sv;
}

// ---------------------------------------------------------------------------
// Combine split partials (log-sum-exp merge) -> xcat cls rows (bf16)
// ---------------------------------------------------------------------------
__global__ __launch_bounds__(64) void cls_reduce(
    const float* __restrict__ part, unsigned short* __restrict__ xcat)
{
    const int h = blockIdx.x, b = blockIdx.y, t = threadIdx.x;
    const float* pb = &part[((size_t)(b * NH_ + h) * NSPLIT) * 68];
    float gm = -1e30f;
    for (int i = 0; i < NSPLIT; ++i) gm = fmaxf(gm, pb[i * 68 + 64]);
    float S = 0.f, acc = 0.f;
    for (int i = 0; i < NSPLIT; ++i) {
        float w = __expf(pb[i * 68 + 64] - gm);
        S   += pb[i * 68 + 65] * w;
        acc += pb[i * 68 + t]  * w;
    }
    xcat[(size_t)(b * NTOK) * C_ + h * 64 + t] = f2us(acc / S);
}

// ---------------------------------------------------------------------------
// v_cls GEMV + broadcast-add (unchanged).
// ---------------------------------------------------------------------------
__global__ __launch_bounds__(256) void add_vcls(
    const unsigned short* __restrict__ xcat, unsigned short* __restrict__ xcatc,
    const unsigned short* __restrict__ kv16, const float* __restrict__ kv32,
    const int* __restrict__ flagp)
{
    __shared__ float xr[768];
    __shared__ float psum[4][64];
    __shared__ float vc[64];

    const int blk = blockIdx.x;
    const int rsp = blockIdx.y;
    const int b   = blk / 12;
    const int c0  = (blk % 12) * 64;
    const int t   = threadIdx.x;
    const int f   = *flagp;

    for (int it = 0; it < 3; ++it) {
        int k = t + it * 256;
        xr[k] = us2f(xcat[(size_t)(b * NTOK) * C_ + k]);
    }
    __syncthreads();

    const int cc = t & 63, kq = t >> 6;
    float p = 0.f;
    for (int k = kq * 192; k < kq * 192 + 192; ++k) {
        size_t wi = (size_t)k * 1536 + 768 + c0 + cc;
        p += xr[k] * (f ? kv32[wi] : us2f(kv16[wi]));
    }
    psum[kq][cc] = p;
    __syncthreads();
    if (t < 64) vc[t] = psum[0][t] + psum[1][t] + psum[2][t] + psum[3][t];
    __syncthreads();

    const int ch8  = (t & 7) * 8;
    const int rsub = t >> 3;
    for (int it = 0; it < 32; ++it) {
        int row = rsp * 1024 + it * 32 + rsub;
        size_t off = (size_t)(b * NTOK + 1 + row) * C_ + c0 + ch8;
        us8 vv = *reinterpret_cast<const us8*>(&xcat[off]);
#pragma unroll
        for (int e2 = 0; e2 < 8; ++e2)
            vv[e2] = f2us(us2f(vv[e2]) + vc[ch8 + e2]);
        *reinterpret_cast<us8*>(&xcatc[off]) = vv;
    }
    if (rsp == 0 && t < 64)
        xcatc[(size_t)(b * NTOK) * C_ + c0 + t] = xcat[(size_t)(b * NTOK) * C_ + c0 + t];
}

// ---------------------------------------------------------------------------
// Workspace plans.
// Small-ws (proven safe, ws >= 51,523,712):
//   [0,128) flag | [128, 37,758,080) qkv_2b | [37,758,080, 41,297,024) qkv_wT
//   [41,297,024, 41,714,816) part | [128, 50,344,064) xcatc (after above die)
//   [50,344,064, 51,523,712) pwT
// Big-ws fused (ws >= 156,168,320):
//   [0,128) flag | [128, 151,031,936) qkv_full (all 8 batches)
//   [151,031,936, 154,570,880) qkv_wT | [154,570,880, 154,988,672) part
//   [154,988,672, 156,168,320) pwT | xcatc overlays [128, ...) after qkv dead
// ---------------------------------------------------------------------------
extern "C" void kernel_launch(void* const* d_in, const int* in_sizes, int n_in,
                              void* d_out, int out_size, void* d_ws, size_t ws_size,
                              hipStream_t stream)
{
    const unsigned short* x16  = (const unsigned short*)d_in[0];
    const float*          x32  = (const float*)d_in[0];
    const unsigned short* m16  = (const unsigned short*)d_in[1];
    const float*          m32  = (const float*)d_in[1];
    const unsigned short* g16  = (const unsigned short*)d_in[2];
    const float*          g32  = (const float*)d_in[2];
    const unsigned short* qw16 = (const unsigned short*)d_in[3];
    const float*          qw32 = (const float*)d_in[3];
    const unsigned short* kv16 = (const unsigned short*)d_in[4];
    const float*          kv32 = (const float*)d_in[4];
    const unsigned short* pw16 = (const unsigned short*)d_in[5];
    const float*          pw32 = (const float*)d_in[5];
    const unsigned short* pb16 = (const unsigned short*)d_in[6];
    const float*          pb32 = (const float*)d_in[6];

    char* ws = (char*)d_ws;
    int*            flag  = (int*)ws;
    unsigned short* xcatc = (unsigned short*)(ws + 128);
    unsigned short* xcat  = (unsigned short*)d_out;

    const bool fused = (ws_size >= (size_t)156168320);

    detect_dtype<<<1, 256, 0, stream>>>((const unsigned int*)d_in[0], flag);

    if (fused) {
        unsigned short* qkv_full = (unsigned short*)(ws + 128);
        unsigned short* qkv_wT   = (unsigned short*)(ws + 151031936);
        float*          part     = (float*)(ws + 154570880);
        unsigned short* pwT      = (unsigned short*)(ws + 154988672);

        transpose_w<<<(2304 * 768 + 255) / 256, 256, 0, stream>>>(
            qw16, qw32, flag, qkv_wT, 768, 2304);
        transpose_w<<<(768 * 768 + 255) / 256, 256, 0, stream>>>(
            pw16, pw32, flag, pwT, 768, 768);

        gemm_bt<<<dim3(18, 257), 256, 0, stream>>>(
            x16, x32, flag, qkv_wT,
            nullptr, nullptr, nullptr,
            qkv_full, nullptr,
            MTOT, 2304, 768, 0);
        win_attn<<<dim3(64, 12, 8), 256, 0, stream>>>(qkv_full, m16, m32, flag, xcat, 0);
        cls_part<<<dim3(12, NSPLIT, 8), 256, 0, stream>>>(
            qkv_full, m16, m32, g16, g32, flag, part, 0);

        cls_reduce<<<dim3(12, 8), 64, 0, stream>>>(part, xcat);
        add_vcls<<<dim3(96, 4), 256, 0, stream>>>(xcat, xcatc, kv16, kv32, flag);

        gemm_bt<<<dim3(6, 257), 256, 0, stream>>>(
            xcatc, nullptr, nullptr, pwT,
            pb16, pb32, flag,
            d_out, flag,
            MTOT, 768, 768, 0);
        return;
    }

    unsigned short* qkv_2b = (unsigned short*)(ws + 128);
    unsigned short* qkv_wT = (unsigned short*)(ws + 37758080);
    float*          part   = (float*)(ws + 41297024);
    unsigned short* pwT    = (unsigned short*)(ws + 50344064);
    const bool fastproj = (ws_size >= (size_t)51523712);

    transpose_w<<<(2304 * 768 + 255) / 256, 256, 0, stream>>>(
        qw16, qw32, flag, qkv_wT, 768, 2304);
    if (fastproj)
        transpose_w<<<(768 * 768 + 255) / 256, 256, 0, stream>>>(
            pw16, pw32, flag, pwT, 768, 768);

    for (int b0 = 0; b0 < B_; b0 += 2) {
        gemm_bt<<<dim3(18, 65), 256, 0, stream>>>(
            x16, x32, flag, qkv_wT,
            nullptr, nullptr, nullptr,
            qkv_2b, nullptr,
            2 * NTOK, 2304, 768, (long)b0 * NTOK);
        win_attn<<<dim3(64, 12, 2), 256, 0, stream>>>(qkv_2b, m16, m32, flag, xcat, b0);
        cls_part<<<dim3(12, NSPLIT, 2), 256, 0, stream>>>(
            qkv_2b, m16, m32, g16, g32, flag, part, b0);
    }

    cls_reduce<<<dim3(12, 8), 64, 0, stream>>>(part, xcat);
    add_vcls<<<dim3(96, 4), 256, 0, stream>>>(xcat, xcatc, kv16, kv32, flag);

    if (fastproj) {
        gemm_bt<<<dim3(6, 257), 256, 0, stream>>>(
            xcatc, nullptr, nullptr, pwT,
            pb16, pb32, flag,
            d_out, flag,
            MTOT, 768, 768, 0);
    } else {
        gemm_univ<<<dim3(6, 257), 256, 0, stream>>>(
            xcatc, nullptr, nullptr, pw16, pw32, flag, 1,
            pb16, pb32, d_out, flag,
            MTOT, 768, 768, 0);
    }
}